// Round 1
// 766.700 us; speedup vs baseline: 1.1788x; 1.1788x over previous
//
#include <hip/hip_runtime.h>
#include <hip/hip_bf16.h>
#include <math.h>

using bf16 = __hip_bfloat16;

typedef short s16x8 __attribute__((ext_vector_type(8)));
typedef float f32x4 __attribute__((ext_vector_type(4)));

// Problem dims (fixed by setup_inputs)
constexpr int Bc = 8, Tc = 1024, Dc = 1024, Hc = 8;
constexpr int NTc = 77, LTc = 768, KRc = 1024, Nc = 2125, Ec = 2048;
constexpr float NEGC = -1000000.0f;

// Transposed K/V layout: [b][feature(1024)][token], row stride NP (16B-aligned)
constexpr int NP = 2128;  // 2125 tokens + 3 pad (zeroed in vT; guarded in kT reads)

// ---- Workspace layout ----
constexpr long F_STATS1 = 0;                    // 16,384
constexpr long F_STATS2 = F_STATS1 + 16384;     // 16,384
constexpr long F_KEYADD = F_STATS2 + 16384;     // 17,000
constexpr long F_VALMUL = F_KEYADD + 17000;     // 17,000
constexpr long F_SILU   = F_VALMUL + 17000;     // 16,384 (cs_m[8192] + cs_inv[8192])
constexpr long F_EO     = F_SILU + 16384;       // 16,384
constexpr long F_ATT    = F_EO + 16384;         // 1,048,576
constexpr long F_END    = F_ATT + 1048576;
// bf16 region
constexpr long KT_SZ   = (long)Bc * Dc * NP;    // 17,432,576
constexpr long B_NORMX = 0;                     // 8,388,608 (reused: att_part fp32, then y16)
constexpr long B_Q     = B_NORMX + 8388608;     // 8,388,608 (reused: s16)
constexpr long B_KT    = B_Q + 8388608;         // kT  [b][d][n]
constexpr long B_VT    = B_KT + KT_SZ;          // vT  [b][l][n] (reused: eo_part fp32 after att)
constexpr long B_NXF   = B_VT + KT_SZ;          // 473,088
constexpr long B_WQ    = B_NXF + 473088;
constexpr long B_WKT   = B_WQ + 1048576;
constexpr long B_WVT   = B_WKT + 786432;
constexpr long B_WKM   = B_WVT + 786432;
constexpr long B_WVM   = B_WKM + 1048576;
constexpr long B_WKR   = B_WVM + 1048576;
constexpr long B_WVR   = B_WKR + 2097152;
constexpr long B_WO    = B_WVR + 1048576;
constexpr long B_END   = B_WO + 1048576;
constexpr size_t WS_NEED = (size_t)F_END * 4 + (size_t)B_END * 2;

__device__ __forceinline__ float b2f(bf16 v) { return __bfloat162float(v); }
__device__ __forceinline__ bf16 f2b(float v) { return __float2bfloat16(v); }
__device__ __forceinline__ short f2s(float v) {
    bf16 h = __float2bfloat16(v);
    return *reinterpret_cast<short*>(&h);
}
__device__ __forceinline__ float us2f(unsigned short u) {
    bf16 h = *reinterpret_cast<bf16*>(&u);
    return __bfloat162float(h);
}
__device__ __forceinline__ void storef(float* p, float v) { *p = v; }
__device__ __forceinline__ void storef(bf16* p, float v) { *p = __float2bfloat16(v); }

// async global->LDS, 16B per lane. LDS dest must be wave-uniform base + lane*16.
typedef __attribute__((address_space(1))) const unsigned int gu32;
typedef __attribute__((address_space(3))) unsigned int lu32;
__device__ __forceinline__ void gl_lds16(const void* g, void* l) {
    __builtin_amdgcn_global_load_lds((gu32*)g, (lu32*)l, 16, 0, 0);
}

__device__ __forceinline__ float2 block_sum2(float s, float s2) {
    #pragma unroll
    for (int off = 32; off > 0; off >>= 1) {
        s  += __shfl_down(s, off, 64);
        s2 += __shfl_down(s2, off, 64);
    }
    __shared__ float sh[4], sh2[4];
    int w = threadIdx.x >> 6, lane = threadIdx.x & 63;
    if (lane == 0) { sh[w] = s; sh2[w] = s2; }
    __syncthreads();
    s = sh[0] + sh[1] + sh[2] + sh[3];
    s2 = sh2[0] + sh2[1] + sh2[2] + sh2[3];
    return make_float2(s, s2);
}

// Row LayerNorm: one block (256 thr) per row
template <typename TO>
__global__ __launch_bounds__(256) void ln_rows(const float* __restrict__ in,
                                               const float* __restrict__ g,
                                               const float* __restrict__ b,
                                               TO* __restrict__ out, int C) {
    long row = blockIdx.x;
    const float* x = in + row * (long)C;
    TO* o = out + row * (long)C;
    float s = 0.f, s2 = 0.f;
    for (int c = threadIdx.x; c < C; c += 256) { float v = x[c]; s += v; s2 += v * v; }
    float2 r = block_sum2(s, s2);
    float mean = r.x / C;
    float var = r.y / C - mean * mean;
    float inv = rsqrtf(var + 1e-5f);
    for (int c = threadIdx.x; c < C; c += 256)
        storef(&o[c], (x[c] - mean) * inv * g[c] + b[c]);
}

// Both retrieval LN stats in one pass over re_motion
__global__ __launch_bounds__(256) void ln_stats_both(const float* __restrict__ motion,
                                                     const float* __restrict__ text,
                                                     float* __restrict__ stats1,
                                                     float* __restrict__ stats2) {
    long row = blockIdx.x;  // b*1024 + k*512 + r
    const float* m = motion + row * 1024;
    const float* tx = text + (row >> 9) * 1024;
    float s = 0.f, s2 = 0.f;
    for (int c = threadIdx.x; c < 1024; c += 256) { float v = m[c]; s += v; s2 += v * v; }
    float2 rm = block_sum2(s, s2);
    __syncthreads();
    float st = 0.f, st2 = 0.f;
    for (int c = threadIdx.x; c < 1024; c += 256) { float v = tx[c]; st += v; st2 += v * v; }
    float2 rt = block_sum2(st, st2);
    if (threadIdx.x == 0) {
        float mean2 = rm.x / 1024.f;
        float var2 = rm.y / 1024.f - mean2 * mean2;
        stats2[2 * row] = mean2;
        stats2[2 * row + 1] = rsqrtf(var2 + 1e-5f);
        float mean1 = (rm.x + rt.x) / 2048.f;
        float var1 = (rm.y + rt.y) / 2048.f - mean1 * mean1;
        stats1[2 * row] = mean1;
        stats1[2 * row + 1] = rsqrtf(var1 + 1e-5f);
    }
}

// Per-(b, n) key additive mask and value multiplicative mask
__global__ __launch_bounds__(256) void prep_masks(const int* __restrict__ cond_type,
                                                  const float* __restrict__ src_mask,
                                                  const float* __restrict__ re_mask,
                                                  float* __restrict__ key_add,
                                                  float* __restrict__ val_mul) {
    int idx = blockIdx.x * 256 + threadIdx.x;
    if (idx >= Bc * Nc) return;
    int b = idx / Nc, n = idx % Nc;
    int ct = cond_type[b];
    float text_ct = ((ct % 10) > 0) ? 1.f : 0.f;
    float retr_ct = ((ct / 10) > 0) ? 1.f : 0.f;
    float add, mul;
    if (n < NTc) {
        add = (1.f - text_ct) * NEGC; mul = text_ct;
    } else if (n < NTc + KRc) {
        float rm = re_mask[b * KRc + (n - NTc)];
        add = (1.f - retr_ct) * NEGC + (1.f - rm) * NEGC;
        mul = retr_ct * rm;
    } else {
        float sm = src_mask[b * Tc + (n - NTc - KRc)];
        add = (1.f - sm) * NEGC; mul = sm;
    }
    key_add[idx] = add;
    val_mul[idx] = mul;
}

// Zero the 3 pad columns of vT (keeps MFMA tail reads finite; kT pad is guarded)
__global__ __launch_bounds__(256) void zero_tail(bf16* __restrict__ vT) {
    int row = blockIdx.x * 256 + threadIdx.x;
    if (row >= Bc * Dc) return;
    bf16* p = vT + (long)row * NP + Nc;
    p[0] = f2b(0.f); p[1] = f2b(0.f); p[2] = f2b(0.f);
}

// Transpose + convert weight: W[K][N] fp32 -> Wt[N][K] bf16(short)
__global__ __launch_bounds__(256) void transpose_w(const float* __restrict__ W,
                                                   short* __restrict__ Wt,
                                                   int K, int N) {
    __shared__ float t[32][33];
    int n0 = blockIdx.x * 32, k0 = blockIdx.y * 32;
    int tx = threadIdx.x & 31, ty = threadIdx.x >> 5;
    #pragma unroll
    for (int i = 0; i < 4; ++i)
        t[ty + i * 8][tx] = W[(long)(k0 + ty + i * 8) * N + n0 + tx];
    __syncthreads();
    #pragma unroll
    for (int i = 0; i < 4; ++i)
        Wt[(long)(n0 + ty + i * 8) * K + k0 + tx] = f2s(t[tx][ty + i * 8]);
}

// ======================= MFMA GEMM (B^T layout, async LDS staging) ==========
// TR=false: C[token][feature] as before.
// TR=true : C^T store — C[feature*ldc + token] (swapped MFMA operands, no LDS bounce).
constexpr int LDK = 64;

template <typename TC, bool TR = false>
__global__ __launch_bounds__(256) void gemm_bt(
    const short* __restrict__ A, int lda, long sA,
    const short* __restrict__ Bt, int ldb,
    const float* __restrict__ bias,
    const float* __restrict__ rowadd, int sRA,
    const float* __restrict__ rowmul, int sRM,
    const float* __restrict__ addC, int ldac, long sAC,
    TC* __restrict__ C, int ldc, long sC,
    int M, int K) {
    int bz = blockIdx.z;
    A += (long)bz * sA;
    C += (long)bz * sC;
    if (rowadd) rowadd += (long)bz * sRA;
    if (rowmul) rowmul += (long)bz * sRM;
    if (addC) addC += (long)bz * sAC;

    const int tm = blockIdx.y * 128;
    const int tn = blockIdx.x * 128;

    __shared__ __align__(16) short As[128 * LDK];
    __shared__ __align__(16) short Bs[128 * LDK];

    int tid = threadIdx.x;
    int lane = tid & 63, wid = tid >> 6;
    int wi = wid >> 1, wj = wid & 1;
    int l16 = lane & 15, quad = lane >> 4;

    f32x4 acc[4][4];
    #pragma unroll
    for (int i = 0; i < 4; ++i)
        #pragma unroll
        for (int j = 0; j < 4; ++j)
            acc[i][j] = (f32x4){0.f, 0.f, 0.f, 0.f};

    auto issue = [&](int k0) {
        #pragma unroll
        for (int p = 0; p < 4; ++p) {
            int e = p * 256 + tid;
            int row = e >> 3, c8 = e & 7;
            int gm = tm + row;
            if (gm >= M) gm = M - 1;  // clamp: garbage rows never stored
            gl_lds16(A + (long)gm * lda + k0 + c8 * 8, &As[row * LDK + c8 * 8]);
            gl_lds16(Bt + (long)(tn + row) * ldb + k0 + c8 * 8, &Bs[row * LDK + c8 * 8]);
        }
    };

    issue(0);
    int kt = 0;
    while (true) {
        __syncthreads();
        #pragma unroll
        for (int kk = 0; kk < 2; ++kk) {
            s16x8 af[4], bfr[4];
            #pragma unroll
            for (int i = 0; i < 4; ++i)
                af[i] = *(const s16x8*)&As[(wi * 64 + i * 16 + l16) * LDK + kk * 32 + quad * 8];
            #pragma unroll
            for (int j = 0; j < 4; ++j)
                bfr[j] = *(const s16x8*)&Bs[(wj * 64 + j * 16 + l16) * LDK + kk * 32 + quad * 8];
            #pragma unroll
            for (int i = 0; i < 4; ++i)
                #pragma unroll
                for (int j = 0; j < 4; ++j) {
                    if constexpr (TR)
                        acc[i][j] = __builtin_amdgcn_mfma_f32_16x16x32_bf16(bfr[j], af[i], acc[i][j], 0, 0, 0);
                    else
                        acc[i][j] = __builtin_amdgcn_mfma_f32_16x16x32_bf16(af[i], bfr[j], acc[i][j], 0, 0, 0);
                }
        }
        int nxt = kt + 64;
        if (nxt >= K) break;
        __syncthreads();
        issue(nxt);
        kt = nxt;
    }

    if constexpr (TR) {
        // acc[i][j]: D-row = feature (tile j, quad*4+r), D-col = token (tile i, l16)
        #pragma unroll
        for (int j = 0; j < 4; ++j) {
            #pragma unroll
            for (int r = 0; r < 4; ++r) {
                int feat = tn + wj * 64 + j * 16 + quad * 4 + r;
                float bf_ = bias ? bias[feat] : 0.f;
                #pragma unroll
                for (int i = 0; i < 4; ++i) {
                    int tok = tm + wi * 64 + i * 16 + l16;
                    if (tok >= M) continue;
                    float v = acc[i][j][r] + bf_ + (rowadd ? rowadd[tok] : 0.f);
                    v *= (rowmul ? rowmul[tok] : 1.f);
                    storef(&C[(long)feat * ldc + tok], v);
                }
            }
        }
    } else {
        #pragma unroll
        for (int i = 0; i < 4; ++i) {
            #pragma unroll
            for (int r = 0; r < 4; ++r) {
                int gm = tm + wi * 64 + i * 16 + quad * 4 + r;
                if (gm >= M) continue;
                float ra = rowadd ? rowadd[gm] : 0.f;
                float rm = rowmul ? rowmul[gm] : 1.f;
                #pragma unroll
                for (int j = 0; j < 4; ++j) {
                    int gn = tn + wj * 64 + j * 16 + l16;
                    float v = acc[i][j][r] + (bias ? bias[gn] : 0.f) + ra;
                    v *= rm;
                    if (addC) v += addC[(long)gm * ldac + gn];
                    storef(&C[(long)gm * ldc + gn], v);
                }
            }
        }
    }
}

// MFMA GEMM with LayerNorm fused into A staging (A via regs->LDS, B async).
template <typename TC, bool TR = false>
__global__ __launch_bounds__(256) void gemm_lnA_mfma(
    const float* __restrict__ motion, const float* __restrict__ text,
    const float* __restrict__ stats,
    const float* __restrict__ g, const float* __restrict__ bvec,
    const short* __restrict__ Bt, int ldb,
    const float* __restrict__ bias,
    const float* __restrict__ rowadd, int sRA,
    const float* __restrict__ rowmul, int sRM,
    TC* __restrict__ C, int ldc, long sC,
    int K) {
    int bz = blockIdx.z;
    C += (long)bz * sC;
    if (rowadd) rowadd += (long)bz * sRA;
    if (rowmul) rowmul += (long)bz * sRM;

    const int tm = blockIdx.y * 128;
    const int tn = blockIdx.x * 128;

    __shared__ __align__(16) short As[128 * LDK];
    __shared__ __align__(16) short Bs[128 * LDK];

    int tid = threadIdx.x;
    int lane = tid & 63, wid = tid >> 6;
    int wi = wid >> 1, wj = wid & 1;
    int l16 = lane & 15, quad = lane >> 4;

    f32x4 acc[4][4];
    #pragma unroll
    for (int i = 0; i < 4; ++i)
        #pragma unroll
        for (int j = 0; j < 4; ++j)
            acc[i][j] = (f32x4){0.f, 0.f, 0.f, 0.f};

    uint4 pa[4];

    auto computeA = [&](int k0) {
        #pragma unroll
        for (int p = 0; p < 4; ++p) {
            int e = p * 256 + tid;
            int row = e >> 3, c8 = e & 7;
            long rg = (long)bz * 1024 + tm + row;
            int c = k0 + c8 * 8;
            const float* src = (c < 1024) ? motion + rg * 1024 + c
                                          : text + (rg >> 9) * 1024 + (c - 1024);
            float4 v0 = *(const float4*)src;
            float4 v1 = *(const float4*)(src + 4);
            float mean = stats[2 * rg], rstd = stats[2 * rg + 1];
            float4 g0 = *(const float4*)&g[c], g1 = *(const float4*)&g[c + 4];
            float4 b0 = *(const float4*)&bvec[c], b1 = *(const float4*)&bvec[c + 4];
            union { short s[8]; uint4 u; } pk;
            pk.s[0] = f2s((v0.x - mean) * rstd * g0.x + b0.x);
            pk.s[1] = f2s((v0.y - mean) * rstd * g0.y + b0.y);
            pk.s[2] = f2s((v0.z - mean) * rstd * g0.z + b0.z);
            pk.s[3] = f2s((v0.w - mean) * rstd * g0.w + b0.w);
            pk.s[4] = f2s((v1.x - mean) * rstd * g1.x + b1.x);
            pk.s[5] = f2s((v1.y - mean) * rstd * g1.y + b1.y);
            pk.s[6] = f2s((v1.z - mean) * rstd * g1.z + b1.z);
            pk.s[7] = f2s((v1.w - mean) * rstd * g1.w + b1.w);
            pa[p] = pk.u;
        }
    };
    auto issueB = [&](int k0) {
        #pragma unroll
        for (int p = 0; p < 4; ++p) {
            int e = p * 256 + tid;
            int row = e >> 3, c8 = e & 7;
            gl_lds16(Bt + (long)(tn + row) * ldb + k0 + c8 * 8, &Bs[row * LDK + c8 * 8]);
        }
    };
    auto storeA = [&]() {
        #pragma unroll
        for (int p = 0; p < 4; ++p) {
            int e = p * 256 + tid;
            int row = e >> 3, c8 = e & 7;
            *(uint4*)&As[row * LDK + c8 * 8] = pa[p];
        }
    };

    issueB(0);
    computeA(0);
    storeA();
    int kt = 0;
    while (true) {
        __syncthreads();
        #pragma unroll
        for (int kk = 0; kk < 2; ++kk) {
            s16x8 af[4], bfr[4];
            #pragma unroll
            for (int i = 0; i < 4; ++i)
                af[i] = *(const s16x8*)&As[(wi * 64 + i * 16 + l16) * LDK + kk * 32 + quad * 8];
            #pragma unroll
            for (int j = 0; j < 4; ++j)
                bfr[j] = *(const s16x8*)&Bs[(wj * 64 + j * 16 + l16) * LDK + kk * 32 + quad * 8];
            #pragma unroll
            for (int i = 0; i < 4; ++i)
                #pragma unroll
                for (int j = 0; j < 4; ++j) {
                    if constexpr (TR)
                        acc[i][j] = __builtin_amdgcn_mfma_f32_16x16x32_bf16(bfr[j], af[i], acc[i][j], 0, 0, 0);
                    else
                        acc[i][j] = __builtin_amdgcn_mfma_f32_16x16x32_bf16(af[i], bfr[j], acc[i][j], 0, 0, 0);
                }
        }
        int nxt = kt + 64;
        if (nxt >= K) break;
        computeA(nxt);
        __syncthreads();
        issueB(nxt);
        storeA();
        kt = nxt;
    }

    if constexpr (TR) {
        #pragma unroll
        for (int j = 0; j < 4; ++j) {
            #pragma unroll
            for (int r = 0; r < 4; ++r) {
                int feat = tn + wj * 64 + j * 16 + quad * 4 + r;
                float bf_ = bias ? bias[feat] : 0.f;
                #pragma unroll
                for (int i = 0; i < 4; ++i) {
                    int tok = tm + wi * 64 + i * 16 + l16;
                    float v = acc[i][j][r] + bf_ + (rowadd ? rowadd[tok] : 0.f);
                    v *= (rowmul ? rowmul[tok] : 1.f);
                    storef(&C[(long)feat * ldc + tok], v);
                }
            }
        }
    } else {
        #pragma unroll
        for (int i = 0; i < 4; ++i) {
            #pragma unroll
            for (int r = 0; r < 4; ++r) {
                int gm = tm + wi * 64 + i * 16 + quad * 4 + r;
                float ra = rowadd ? rowadd[gm] : 0.f;
                float rm = rowmul ? rowmul[gm] : 1.f;
                #pragma unroll
                for (int j = 0; j < 4; ++j) {
                    int gn = tn + wj * 64 + j * 16 + l16;
                    float v = acc[i][j][r] + (bias ? bias[gn] : 0.f) + ra;
                    v *= rm;
                    storef(&C[(long)gm * ldc + gn], v);
                }
            }
        }
    }
}

// eo split-K
__global__ __launch_bounds__(256) void eo_partial(const float* __restrict__ emb,
                                                  const float* __restrict__ We,
                                                  float* __restrict__ part) {
    int nb = blockIdx.x;
    int ks = blockIdx.y;
    int n = nb * 256 + threadIdx.x;
    int k0 = ks * 64;
    __shared__ float a_s[8][64];
    for (int idx = threadIdx.x; idx < 512; idx += 256) {
        int b = idx >> 6, kk = idx & 63;
        float v = emb[b * 2048 + k0 + kk];
        a_s[b][kk] = v / (1.f + expf(-v));
    }
    __syncthreads();
    float acc[8] = {};
    for (int kk = 0; kk < 64; ++kk) {
        float w = We[(long)(k0 + kk) * 2048 + n];
        #pragma unroll
        for (int b = 0; b < 8; ++b) acc[b] = fmaf(a_s[b][kk], w, acc[b]);
    }
    #pragma unroll
    for (int b = 0; b < 8; ++b) part[((long)ks * 8 + b) * 2048 + n] = acc[b];
}

__global__ __launch_bounds__(256) void eo_reduce(const float* __restrict__ part,
                                                 const float* __restrict__ be,
                                                 float* __restrict__ eo) {
    int idx = blockIdx.x * 256 + threadIdx.x;
    int n = idx & 2047, b = idx >> 11;
    float s = be[n];
    #pragma unroll 8
    for (int ks = 0; ks < 32; ++ks) s += part[((long)ks * 8 + b) * 2048 + n];
    eo[idx] = s;
}

// q softmax over head dim (128): one wave per row, 2 elems/lane.
__global__ __launch_bounds__(256) void softmax_head(bf16* __restrict__ q) {
    long row = (long)blockIdx.x * 4 + (threadIdx.x >> 6);
    int lane = threadIdx.x & 63;
    bf16* p = q + row * 128 + lane * 2;
    float v0 = b2f(p[0]), v1 = b2f(p[1]);
    float mx = fmaxf(v0, v1);
    #pragma unroll
    for (int off = 32; off > 0; off >>= 1) mx = fmaxf(mx, __shfl_xor(mx, off, 64));
    float e0 = expf(v0 - mx), e1 = expf(v1 - mx);
    float s = e0 + e1;
    #pragma unroll
    for (int off = 32; off > 0; off >>= 1) s += __shfl_xor(s, off, 64);
    float inv = 1.f / s;
    p[0] = f2b(e0 * inv);
    p[1] = f2b(e1 * inv);
}

// key softmax column stats over tokens — now a ROW reduction on kT[b][d][n].
// One wave per (b,d) row: max then sumexp, coalesced bf16x8 loads.
__global__ __launch_bounds__(256) void ksm_rows(const bf16* __restrict__ kT,
                                                float* __restrict__ cs_m,
                                                float* __restrict__ cs_inv) {
    int row = blockIdx.x * 4 + (threadIdx.x >> 6);  // b*1024 + feature
    int lane = threadIdx.x & 63;
    const s16x8* p8 = (const s16x8*)(kT + (long)row * NP);
    float m = -3.0e38f;
    for (int c = lane; c < NP / 8; c += 64) {
        s16x8 raw = p8[c];
        int n0 = c * 8;
        #pragma unroll
        for (int j = 0; j < 8; ++j)
            if (n0 + j < Nc) m = fmaxf(m, us2f((unsigned short)raw[j]));
    }
    #pragma unroll
    for (int off = 32; off > 0; off >>= 1) m = fmaxf(m, __shfl_xor(m, off, 64));
    float s = 0.f;
    for (int c = lane; c < NP / 8; c += 64) {
        s16x8 raw = p8[c];
        int n0 = c * 8;
        #pragma unroll
        for (int j = 0; j < 8; ++j)
            if (n0 + j < Nc) s += __expf(us2f((unsigned short)raw[j]) - m);
    }
    #pragma unroll
    for (int off = 32; off > 0; off >>= 1) s += __shfl_xor(s, off, 64);
    if (lane == 0) { cs_m[row] = m; cs_inv[row] = 1.f / s; }
}

// att_part[split][bh][d][l] = sum_{n in split} exp(kT[bd][n]-m_d) * vT[bl][n]
// MFMA batched GEMM: per (b,h): C[128][128] = A(128,K) @ B^T(128,K), K = tokens.
// A = exp(kT - m) reg-staged (guarded n<Nc); B = vT async-staged (source-clamped).
constexpr int ATT_SPLIT = 4;
__global__ __launch_bounds__(256) void att_gemm(const bf16* __restrict__ kTb,
                                                const bf16* __restrict__ vTb,
                                                const float* __restrict__ cs_m,
                                                float* __restrict__ att_part) {
    int bh = blockIdx.x;
    int split = blockIdx.y;
    int b = bh >> 3, h = bh & 7;
    const short* A  = (const short*)kTb + ((long)b * 1024 + h * 128) * NP;
    const short* Bt = (const short*)vTb + ((long)b * 1024 + h * 128) * NP;
    float* ap = att_part + ((long)split * 64 + bh) * 16384;

    __shared__ __align__(16) short As[128 * LDK];
    __shared__ __align__(16) short Bs[128 * LDK];
    __shared__ float ms[128];

    int tid = threadIdx.x;
    if (tid < 128) ms[tid] = cs_m[(long)b * 1024 + h * 128 + tid];

    int lane = tid & 63, wid = tid >> 6;
    int wi = wid >> 1, wj = wid & 1;
    int l16 = lane & 15, quad = lane >> 4;

    f32x4 acc[4][4];
    #pragma unroll
    for (int i = 0; i < 4; ++i)
        #pragma unroll
        for (int j = 0; j < 4; ++j)
            acc[i][j] = (f32x4){0.f, 0.f, 0.f, 0.f};

    uint4 pa[4];
    auto computeA = [&](int k0) {
        #pragma unroll
        for (int p = 0; p < 4; ++p) {
            int e = p * 256 + tid;
            int row = e >> 3, c8 = e & 7;
            int n0 = k0 + c8 * 8;
            union { short s[8]; uint4 u; } pk;
            if (n0 >= Nc) {
                pk.u = (uint4){0u, 0u, 0u, 0u};
            } else {
                float m = ms[row];
                s16x8 raw = *(const s16x8*)(A + (long)row * NP + n0);
                #pragma unroll
                for (int j = 0; j < 8; ++j) {
                    float v = (n0 + j < Nc) ? __expf(us2f((unsigned short)raw[j]) - m) : 0.f;
                    pk.s[j] = f2s(v);
                }
            }
            pa[p] = pk.u;
        }
    };
    auto issueB = [&](int k0) {
        #pragma unroll
        for (int p = 0; p < 4; ++p) {
            int e = p * 256 + tid;
            int row = e >> 3, c8 = e & 7;
            int n0 = k0 + c8 * 8;
            if (n0 > NP - 8) n0 = NP - 8;  // clamp: A is zero there, values just must be finite
            gl_lds16(Bt + (long)row * NP + n0, &Bs[row * LDK + c8 * 8]);
        }
    };
    auto storeA = [&]() {
        #pragma unroll
        for (int p = 0; p < 4; ++p) {
            int e = p * 256 + tid;
            int row = e >> 3, c8 = e & 7;
            *(uint4*)&As[row * LDK + c8 * 8] = pa[p];
        }
    };

    // 34 K-steps total, split {9,9,8,8}
    int st = (split < 2) ? split * 9 : 18 + (split - 2) * 8;
    int cnt = (split < 2) ? 9 : 8;
    int kt = st * 64;
    int kend = kt + cnt * 64;

    __syncthreads();  // ms ready
    issueB(kt);
    computeA(kt);
    storeA();
    while (true) {
        __syncthreads();
        #pragma unroll
        for (int kk = 0; kk < 2; ++kk) {
            s16x8 af[4], bfr[4];
            #pragma unroll
            for (int i = 0; i < 4; ++i)
                af[i] = *(const s16x8*)&As[(wi * 64 + i * 16 + l16) * LDK + kk * 32 + quad * 8];
            #pragma unroll
            for (int j = 0; j < 4; ++j)
                bfr[j] = *(const s16x8*)&Bs[(wj * 64 + j * 16 + l16) * LDK + kk * 32 + quad * 8];
            #pragma unroll
            for (int i = 0; i < 4; ++i)
                #pragma unroll
                for (int j = 0; j < 4; ++j)
                    acc[i][j] = __builtin_amdgcn_mfma_f32_16x16x32_bf16(af[i], bfr[j], acc[i][j], 0, 0, 0);
        }
        int nxt = kt + 64;
        if (nxt >= kend) break;
        computeA(nxt);
        __syncthreads();
        issueB(nxt);
        storeA();
        kt = nxt;
    }

    #pragma unroll
    for (int i = 0; i < 4; ++i) {
        #pragma unroll
        for (int r = 0; r < 4; ++r) {
            int gm = wi * 64 + i * 16 + quad * 4 + r;  // d
            #pragma unroll
            for (int j = 0; j < 4; ++j) {
                int gn = wj * 64 + j * 16 + l16;  // l
                ap[gm * 128 + gn] = acc[i][j][r];
            }
        }
    }
}

// reduce + apply per-d 1/sum
__global__ __launch_bounds__(256) void reduce_att(const float* __restrict__ att_part,
                                                  const float* __restrict__ cs_inv,
                                                  float* __restrict__ att) {
    long idx = (long)blockIdx.x * 256 + threadIdx.x;
    if (idx >= (long)64 * 16384) return;
    float s = 0.f;
    #pragma unroll
    for (int sp = 0; sp < ATT_SPLIT; ++sp) s += att_part[(long)sp * 64 * 16384 + idx];
    int bh = (int)(idx >> 14);
    int d = (int)((idx >> 7) & 127);
    int b = bh >> 3, h = bh & 7;
    att[idx] = s * cs_inv[b * Dc + h * 128 + d];
}

// y[b,t,h*128+l] = sum_d q[b,t,h*128+d] * att[bh][d][l]
__global__ __launch_bounds__(256) void y_kernel(const bf16* __restrict__ q,
                                                const float* __restrict__ att,
                                                bf16* __restrict__ y) {
    int bh = blockIdx.y;
    int b = bh >> 3, h = bh & 7;
    const bf16* qb = q + (long)b * Tc * Dc + h * 128;
    const float* ab = att + (long)bh * 16384;
    bf16* yb = y + (long)b * Tc * Dc + h * 128;
    int t0 = blockIdx.x * 64;
    __shared__ float qs[16][68];
    __shared__ float as[16][128];
    int tid = threadIdx.x, tx = tid & 15, ty = tid >> 4;
    float acc[4][8] = {};
    for (int k0 = 0; k0 < 128; k0 += 16) {
        for (int e = tid; e < 1024; e += 256) {
            int m = e >> 4, k = e & 15;
            qs[k][m] = b2f(qb[(long)(t0 + m) * Dc + k0 + k]);
        }
        for (int e = tid; e < 2048; e += 256) {
            int k = e >> 7, n = e & 127;
            as[k][n] = ab[(k0 + k) * 128 + n];
        }
        __syncthreads();
        #pragma unroll
        for (int k = 0; k < 16; ++k) {
            float a[4], w[8];
            #pragma unroll
            for (int i = 0; i < 4; ++i) a[i] = qs[k][ty * 4 + i];
            #pragma unroll
            for (int j = 0; j < 8; ++j) w[j] = as[k][tx * 8 + j];
            #pragma unroll
            for (int i = 0; i < 4; ++i)
                #pragma unroll
                for (int j = 0; j < 8; ++j)
                    acc[i][j] = fmaf(a[i], w[j], acc[i][j]);
        }
        __syncthreads();
    }
    for (int i = 0; i < 4; ++i)
        for (int j = 0; j < 8; ++j)
            yb[(long)(t0 + ty * 4 + i) * Dc + tx * 8 + j] = f2b(acc[i][j]);
}

// s = silu( LN(y)*(1+scale) + shift )
__global__ __launch_bounds__(256) void film_kernel(const bf16* __restrict__ y,
                                                   const float* __restrict__ eo,
                                                   const float* __restrict__ g,
                                                   const float* __restrict__ bta,
                                                   bf16* __restrict__ s) {
    long row = blockIdx.x;
    int b = (int)(row >> 10);
    const bf16* yr = y + row * Dc;
    float sum = 0.f, sum2 = 0.f;
    for (int c = threadIdx.x; c < Dc; c += 256) { float v = b2f(yr[c]); sum += v; sum2 += v * v; }
    float2 r = block_sum2(sum, sum2);
    float mean = r.x / Dc;
    float var = r.y / Dc - mean * mean;
    float inv = rsqrtf(var + 1e-5f);
    const float* sc = eo + (long)b * 2048;
    const float* sf = sc + 1024;
    bf16* so = s + row * Dc;
    for (int c = threadIdx.x; c < Dc; c += 256) {
        float v = (b2f(yr[c]) - mean) * inv * g[c] + bta[c];
        v = v * (1.f + sc[c]) + sf[c];
        so[c] = f2b(v / (1.f + expf(-v)));
    }
}

extern "C" void kernel_launch(void* const* d_in, const int* in_sizes, int n_in,
                              void* d_out, int out_size, void* d_ws, size_t ws_size,
                              hipStream_t stream) {
    if (ws_size < WS_NEED) return;

    const float* x         = (const float*)d_in[0];
    const float* xf        = (const float*)d_in[1];
    const float* emb       = (const float*)d_in[2];
    const float* src_mask  = (const float*)d_in[3];
    const int*   cond_type = (const int*)d_in[4];
    const float* re_motion = (const float*)d_in[5];
    const float* re_text   = (const float*)d_in[6];
    const float* re_mask   = (const float*)d_in[7];
    const float* ln_g  = (const float*)d_in[8];
    const float* ln_b  = (const float*)d_in[9];
    const float* tln_g = (const float*)d_in[10];
    const float* tln_b = (const float*)d_in[11];
    const float* rn1_g = (const float*)d_in[12];
    const float* rn1_b = (const float*)d_in[13];
    const float* rn2_g = (const float*)d_in[14];
    const float* rn2_b = (const float*)d_in[15];
    const float* Wq  = (const float*)d_in[16];
    const float* bq  = (const float*)d_in[17];
    const float* Wkt = (const float*)d_in[18];
    const float* bkt = (const float*)d_in[19];
    const float* Wvt = (const float*)d_in[20];
    const float* bvt = (const float*)d_in[21];
    const float* Wkm = (const float*)d_in[22];
    const float* bkm = (const float*)d_in[23];
    const float* Wvm = (const float*)d_in[24];
    const float* bvm = (const float*)d_in[25];
    const float* Wkr = (const float*)d_in[26];
    const float* bkr = (const float*)d_in[27];
    const float* Wvr = (const float*)d_in[28];
    const float* bvr = (const float*)d_in[29];
    const float* We  = (const float*)d_in[30];
    const float* be  = (const float*)d_in[31];
    const float* sln_g = (const float*)d_in[32];
    const float* sln_b = (const float*)d_in[33];
    const float* Wo  = (const float*)d_in[34];
    const float* bo  = (const float*)d_in[35];

    float* ws = (float*)d_ws;
    float* stats1   = ws + F_STATS1;
    float* stats2   = ws + F_STATS2;
    float* key_add  = ws + F_KEYADD;
    float* val_mul  = ws + F_VALMUL;
    float* cs_m     = ws + F_SILU;         // 8192
    float* cs_inv   = cs_m + Bc * Dc;      // 8192
    float* eo       = ws + F_EO;
    float* att      = ws + F_ATT;
    bf16* wb = (bf16*)(ws + F_END);
    bf16* norm_x16 = wb + B_NORMX;
    bf16* q16      = wb + B_Q;
    bf16* kT16     = wb + B_KT;
    bf16* vT16     = wb + B_VT;
    bf16* nxf16    = wb + B_NXF;
    short* WtQ  = (short*)(wb + B_WQ);
    short* WtKT = (short*)(wb + B_WKT);
    short* WtVT = (short*)(wb + B_WVT);
    short* WtKM = (short*)(wb + B_WKM);
    short* WtVM = (short*)(wb + B_WVM);
    short* WtKR = (short*)(wb + B_WKR);
    short* WtVR = (short*)(wb + B_WVR);
    short* WtO  = (short*)(wb + B_WO);
    float* att_part = (float*)(wb + B_NORMX);  // overlays norm_x16 (dead by then)
    bf16* y16 = wb + B_NORMX;                  // written after att_part consumed
    bf16* s16 = q16;                           // q dead after y_kernel
    float* eo_part = (float*)(wb + B_VT);      // overlays vT16 (dead after att_gemm)

    float* out = (float*)d_out;
    const long sKT = (long)Dc * NP;            // batch stride of kT/vT (rows of 1024 features)

    // 1. LayerNorms + stats
    ln_rows<bf16><<<dim3(Bc * Tc), dim3(256), 0, stream>>>(x, ln_g, ln_b, norm_x16, Dc);
    ln_rows<bf16><<<dim3(Bc * NTc), dim3(256), 0, stream>>>(xf, tln_g, tln_b, nxf16, LTc);
    ln_stats_both<<<dim3(Bc * KRc), dim3(256), 0, stream>>>(re_motion, re_text, stats1, stats2);

    // 2. Masks + vT pad zero-fill
    prep_masks<<<dim3((Bc * Nc + 255) / 256), dim3(256), 0, stream>>>(
        cond_type, src_mask, re_mask, key_add, val_mul);
    zero_tail<<<dim3((Bc * Dc + 255) / 256), dim3(256), 0, stream>>>(vT16);

    // 3. Weight transposes
    transpose_w<<<dim3(32, 32), dim3(256), 0, stream>>>(Wq, WtQ, 1024, 1024);
    transpose_w<<<dim3(32, 24), dim3(256), 0, stream>>>(Wkt, WtKT, 768, 1024);
    transpose_w<<<dim3(32, 24), dim3(256), 0, stream>>>(Wvt, WtVT, 768, 1024);
    transpose_w<<<dim3(32, 32), dim3(256), 0, stream>>>(Wkm, WtKM, 1024, 1024);
    transpose_w<<<dim3(32, 32), dim3(256), 0, stream>>>(Wvm, WtVM, 1024, 1024);
    transpose_w<<<dim3(32, 64), dim3(256), 0, stream>>>(Wkr, WtKR, 2048, 1024);
    transpose_w<<<dim3(32, 32), dim3(256), 0, stream>>>(Wvr, WtVR, 1024, 1024);
    transpose_w<<<dim3(32, 32), dim3(256), 0, stream>>>(Wo, WtO, 1024, 1024);

    // 4. MFMA GEMMs — key/value go to TRANSPOSED [b][feature][token] layout
    gemm_bt<bf16, false><<<dim3(8, 64, 1), dim3(256), 0, stream>>>(
        (const short*)norm_x16, Dc, 0, WtQ, 1024, bq, nullptr, 0, nullptr, 0,
        nullptr, 0, 0, q16, Dc, 0, Bc * Tc, 1024);
    gemm_bt<bf16, true><<<dim3(8, 1, Bc), dim3(256), 0, stream>>>(
        (const short*)nxf16, LTc, (long)NTc * LTc, WtKT, 768, bkt,
        key_add + 0, Nc, nullptr, 0, nullptr, 0, 0,
        kT16 + 0, NP, sKT, NTc, 768);
    gemm_lnA_mfma<bf16, true><<<dim3(8, 8, Bc), dim3(256), 0, stream>>>(
        re_motion, re_text, stats1, rn1_g, rn1_b, WtKR, 2048, bkr,
        key_add + NTc, Nc, nullptr, 0, kT16 + NTc, NP, sKT, 2048);
    gemm_bt<bf16, true><<<dim3(8, 8, Bc), dim3(256), 0, stream>>>(
        (const short*)norm_x16, Dc, (long)Tc * Dc, WtKM, 1024, bkm,
        key_add + NTc + KRc, Nc, nullptr, 0, nullptr, 0, 0,
        kT16 + NTc + KRc, NP, sKT, Tc, 1024);
    gemm_bt<bf16, true><<<dim3(8, 1, Bc), dim3(256), 0, stream>>>(
        (const short*)nxf16, LTc, (long)NTc * LTc, WtVT, 768, bvt,
        nullptr, 0, val_mul + 0, Nc, nullptr, 0, 0,
        vT16 + 0, NP, sKT, NTc, 768);
    gemm_lnA_mfma<bf16, true><<<dim3(8, 8, Bc), dim3(256), 0, stream>>>(
        re_motion, nullptr, stats2, rn2_g, rn2_b, WtVR, 1024, bvr,
        nullptr, 0, val_mul + NTc, Nc, vT16 + NTc, NP, sKT, 1024);
    gemm_bt<bf16, true><<<dim3(8, 8, Bc), dim3(256), 0, stream>>>(
        (const short*)norm_x16, Dc, (long)Tc * Dc, WtVM, 1024, bvm,
        nullptr, 0, val_mul + NTc + KRc, Nc, nullptr, 0, 0,
        vT16 + NTc + KRc, NP, sKT, Tc, 1024);

    // 5. Softmaxes: q in place; key column stats via row reduction on kT
    softmax_head<<<dim3(Bc * Tc * Hc / 4), dim3(256), 0, stream>>>(q16);
    ksm_rows<<<dim3(Bc * Dc / 4), dim3(256), 0, stream>>>(kT16, cs_m, cs_inv);

    // 6. att = p^T v as batched MFMA GEMM (exp fused into A staging), K-split 4
    att_gemm<<<dim3(Bc * Hc, ATT_SPLIT), dim3(256), 0, stream>>>(kT16, vT16, cs_m, att_part);
    reduce_att<<<dim3((64 * 16384 + 255) / 256), dim3(256), 0, stream>>>(att_part, cs_inv, att);

    // 7. y = q @ att
    y_kernel<<<dim3(Tc / 64, Bc * Hc), dim3(256), 0, stream>>>(q16, att, y16);

    // 8. eo = silu(emb) @ We + be
    eo_partial<<<dim3(8, 32), dim3(256), 0, stream>>>(emb, We, eo_part);
    eo_reduce<<<dim3(64), dim3(256), 0, stream>>>(eo_part, be, eo);

    // 9. FiLM + silu
    film_kernel<<<dim3(Bc * Tc), dim3(256), 0, stream>>>(y16, eo, sln_g, sln_b, s16);

    // 10. out = x + s @ Wo + bo
    gemm_bt<float, false><<<dim3(8, 64, 1), dim3(256), 0, stream>>>(
        (const short*)s16, Dc, 0, WtO, 1024, bo, nullptr, 0, nullptr, 0,
        x, Dc, 0, out, Dc, 0, Bc * Tc, 1024);
}

// Round 2
// 709.380 us; speedup vs baseline: 1.2740x; 1.0808x over previous
//
#include <hip/hip_runtime.h>
#include <hip/hip_bf16.h>
#include <math.h>

using bf16 = __hip_bfloat16;

typedef short s16x8 __attribute__((ext_vector_type(8)));
typedef short s16x4 __attribute__((ext_vector_type(4)));
typedef float f32x4 __attribute__((ext_vector_type(4)));

// Problem dims (fixed by setup_inputs)
constexpr int Bc = 8, Tc = 1024, Dc = 1024, Hc = 8;
constexpr int NTc = 77, LTc = 768, KRc = 1024, Nc = 2125, Ec = 2048;
constexpr float NEGC = -1000000.0f;

// Transposed K/V layout: [b][feature(1024)][token], row stride NP (16B-aligned)
constexpr int NP = 2128;  // 2125 tokens + 3 pad (zeroed in vT; guarded in kT reads)

// ---- Workspace layout ----
constexpr long F_STATS1 = 0;                    // 16,384
constexpr long F_STATS2 = F_STATS1 + 16384;     // 16,384
constexpr long F_KEYADD = F_STATS2 + 16384;     // 17,000
constexpr long F_VALMUL = F_KEYADD + 17000;     // 17,000
constexpr long F_SILU   = F_VALMUL + 17000;     // 16,384 (cs_m[8192] + cs_inv[8192])
constexpr long F_EO     = F_SILU + 16384;       // 16,384
constexpr long F_ATT    = F_EO + 16384;         // 1,048,576 (holds attT bf16 2MB)
constexpr long F_END    = F_ATT + 1048576;
// bf16 region
constexpr long KT_SZ   = (long)Bc * Dc * NP;    // 17,432,576
constexpr long B_NORMX = 0;                     // 8,388,608 (reused: att_part fp32, then y16)
constexpr long B_Q     = B_NORMX + 8388608;     // 8,388,608 (ren2 first, then q16, then s16)
constexpr long B_KT    = B_Q + 8388608;         // kT  [b][d][n]
constexpr long B_VT    = B_KT + KT_SZ;          // vT  [b][l][n] (reused: eo_part fp32 after att)
constexpr long B_NXF   = B_VT + KT_SZ;          // 473,088
constexpr long B_WQ    = B_NXF + 473088;
constexpr long B_WKT   = B_WQ + 1048576;
constexpr long B_WVT   = B_WKT + 786432;
constexpr long B_WKM   = B_WVT + 786432;
constexpr long B_WVM   = B_WKM + 1048576;
constexpr long B_WKR   = B_WVM + 1048576;
constexpr long B_WVR   = B_WKR + 2097152;
constexpr long B_WO    = B_WVR + 1048576;
constexpr long B_END   = B_WO + 1048576;
constexpr size_t WS_NEED = (size_t)F_END * 4 + (size_t)B_END * 2;

__device__ __forceinline__ float b2f(bf16 v) { return __bfloat162float(v); }
__device__ __forceinline__ bf16 f2b(float v) { return __float2bfloat16(v); }
__device__ __forceinline__ short f2s(float v) {
    bf16 h = __float2bfloat16(v);
    return *reinterpret_cast<short*>(&h);
}
__device__ __forceinline__ float us2f(unsigned short u) {
    bf16 h = *reinterpret_cast<bf16*>(&u);
    return __bfloat162float(h);
}
__device__ __forceinline__ void storef(float* p, float v) { *p = v; }
__device__ __forceinline__ void storef(bf16* p, float v) { *p = __float2bfloat16(v); }

// async global->LDS, 16B per lane. LDS dest must be wave-uniform base + lane*16.
typedef __attribute__((address_space(1))) const unsigned int gu32;
typedef __attribute__((address_space(3))) unsigned int lu32;
__device__ __forceinline__ void gl_lds16(const void* g, void* l) {
    __builtin_amdgcn_global_load_lds((gu32*)g, (lu32*)l, 16, 0, 0);
}

__device__ __forceinline__ float2 block_sum2(float s, float s2) {
    #pragma unroll
    for (int off = 32; off > 0; off >>= 1) {
        s  += __shfl_down(s, off, 64);
        s2 += __shfl_down(s2, off, 64);
    }
    __shared__ float sh[4], sh2[4];
    int w = threadIdx.x >> 6, lane = threadIdx.x & 63;
    if (lane == 0) { sh[w] = s; sh2[w] = s2; }
    __syncthreads();
    s = sh[0] + sh[1] + sh[2] + sh[3];
    s2 = sh2[0] + sh2[1] + sh2[2] + sh2[3];
    return make_float2(s, s2);
}

// Row LayerNorm: one block (256 thr) per row
template <typename TO>
__global__ __launch_bounds__(256) void ln_rows(const float* __restrict__ in,
                                               const float* __restrict__ g,
                                               const float* __restrict__ b,
                                               TO* __restrict__ out, int C) {
    long row = blockIdx.x;
    const float* x = in + row * (long)C;
    TO* o = out + row * (long)C;
    float s = 0.f, s2 = 0.f;
    for (int c = threadIdx.x; c < C; c += 256) { float v = x[c]; s += v; s2 += v * v; }
    float2 r = block_sum2(s, s2);
    float mean = r.x / C;
    float var = r.y / C - mean * mean;
    float inv = rsqrtf(var + 1e-5f);
    for (int c = threadIdx.x; c < C; c += 256)
        storef(&o[c], (x[c] - mean) * inv * g[c] + b[c]);
}

// Both retrieval LN stats in one pass over re_motion
__global__ __launch_bounds__(256) void ln_stats_both(const float* __restrict__ motion,
                                                     const float* __restrict__ text,
                                                     float* __restrict__ stats1,
                                                     float* __restrict__ stats2) {
    long row = blockIdx.x;  // b*1024 + k*512 + r
    const float* m = motion + row * 1024;
    const float* tx = text + (row >> 9) * 1024;
    float s = 0.f, s2 = 0.f;
    for (int c = threadIdx.x; c < 1024; c += 256) { float v = m[c]; s += v; s2 += v * v; }
    float2 rm = block_sum2(s, s2);
    __syncthreads();
    float st = 0.f, st2 = 0.f;
    for (int c = threadIdx.x; c < 1024; c += 256) { float v = tx[c]; st += v; st2 += v * v; }
    float2 rt = block_sum2(st, st2);
    if (threadIdx.x == 0) {
        float mean2 = rm.x / 1024.f;
        float var2 = rm.y / 1024.f - mean2 * mean2;
        stats2[2 * row] = mean2;
        stats2[2 * row + 1] = rsqrtf(var2 + 1e-5f);
        float mean1 = (rm.x + rt.x) / 2048.f;
        float var1 = (rm.y + rt.y) / 2048.f - mean1 * mean1;
        stats1[2 * row] = mean1;
        stats1[2 * row + 1] = rsqrtf(var1 + 1e-5f);
    }
}

// Materialize normalized retrieval operands as bf16 (once, instead of per-n-tile in GEMM):
// ren1[row][0:1024]   = LN1(motion)   part, ren1[row][1024:2048] = LN1(text) part
// ren2[row][0:1024]   = LN2(motion)
__device__ __forceinline__ s16x4 pack4(float4 v, float mean, float rstd, float4 g, float4 b) {
    s16x4 o;
    o[0] = f2s((v.x - mean) * rstd * g.x + b.x);
    o[1] = f2s((v.y - mean) * rstd * g.y + b.y);
    o[2] = f2s((v.z - mean) * rstd * g.z + b.z);
    o[3] = f2s((v.w - mean) * rstd * g.w + b.w);
    return o;
}
__global__ __launch_bounds__(256) void materialize_ren(
    const float* __restrict__ motion, const float* __restrict__ text,
    const float* __restrict__ stats1, const float* __restrict__ stats2,
    const float* __restrict__ g1, const float* __restrict__ b1,
    const float* __restrict__ g2, const float* __restrict__ b2,
    bf16* __restrict__ ren1, bf16* __restrict__ ren2) {
    long row = blockIdx.x;  // b*1024 + kr
    int c = threadIdx.x * 4;
    const float* mrow = motion + row * 1024;
    const float* trow = text + (row >> 9) * 1024;
    float m1 = stats1[2 * row], r1 = stats1[2 * row + 1];
    float m2 = stats2[2 * row], r2 = stats2[2 * row + 1];
    float4 mv = *(const float4*)(mrow + c);
    float4 tv = *(const float4*)(trow + c);
    float4 g1m = *(const float4*)(g1 + c),        b1m = *(const float4*)(b1 + c);
    float4 g1t = *(const float4*)(g1 + 1024 + c), b1t = *(const float4*)(b1 + 1024 + c);
    float4 g2m = *(const float4*)(g2 + c),        b2m = *(const float4*)(b2 + c);
    *(s16x4*)((short*)ren1 + row * 2048 + c)        = pack4(mv, m1, r1, g1m, b1m);
    *(s16x4*)((short*)ren1 + row * 2048 + 1024 + c) = pack4(tv, m1, r1, g1t, b1t);
    *(s16x4*)((short*)ren2 + row * 1024 + c)        = pack4(mv, m2, r2, g2m, b2m);
}

// Per-(b, n) key additive mask and value multiplicative mask
__global__ __launch_bounds__(256) void prep_masks(const int* __restrict__ cond_type,
                                                  const float* __restrict__ src_mask,
                                                  const float* __restrict__ re_mask,
                                                  float* __restrict__ key_add,
                                                  float* __restrict__ val_mul) {
    int idx = blockIdx.x * 256 + threadIdx.x;
    if (idx >= Bc * Nc) return;
    int b = idx / Nc, n = idx % Nc;
    int ct = cond_type[b];
    float text_ct = ((ct % 10) > 0) ? 1.f : 0.f;
    float retr_ct = ((ct / 10) > 0) ? 1.f : 0.f;
    float add, mul;
    if (n < NTc) {
        add = (1.f - text_ct) * NEGC; mul = text_ct;
    } else if (n < NTc + KRc) {
        float rm = re_mask[b * KRc + (n - NTc)];
        add = (1.f - retr_ct) * NEGC + (1.f - rm) * NEGC;
        mul = retr_ct * rm;
    } else {
        float sm = src_mask[b * Tc + (n - NTc - KRc)];
        add = (1.f - sm) * NEGC; mul = sm;
    }
    key_add[idx] = add;
    val_mul[idx] = mul;
}

// Zero the 3 pad columns of vT (keeps MFMA tail reads finite; kT pad is guarded)
__global__ __launch_bounds__(256) void zero_tail(bf16* __restrict__ vT) {
    int row = blockIdx.x * 256 + threadIdx.x;
    if (row >= Bc * Dc) return;
    bf16* p = vT + (long)row * NP + Nc;
    p[0] = f2b(0.f); p[1] = f2b(0.f); p[2] = f2b(0.f);
}

// All 8 weight transposes in ONE launch: W[K][1024] fp32 -> Wt[1024][K] bf16
// k-tile counts: Q:32 KT:24 VT:24 KM:32 VM:32 KR:64 VR:32 O:32 (cum 272)
__global__ __launch_bounds__(256) void transpose_all(
    const float* __restrict__ Wq,  const float* __restrict__ Wkt,
    const float* __restrict__ Wvt, const float* __restrict__ Wkm,
    const float* __restrict__ Wvm, const float* __restrict__ Wkr,
    const float* __restrict__ Wvr, const float* __restrict__ Wo,
    short* __restrict__ WtQ,  short* __restrict__ WtKT,
    short* __restrict__ WtVT, short* __restrict__ WtKM,
    short* __restrict__ WtVM, short* __restrict__ WtKR,
    short* __restrict__ WtVR, short* __restrict__ WtO) {
    __shared__ float t[32][33];
    int sy = blockIdx.y;
    const float* W; short* Wt; int K; int ky;
    if (sy < 32)       { W = Wq;  Wt = WtQ;  K = 1024; ky = sy; }
    else if (sy < 56)  { W = Wkt; Wt = WtKT; K = 768;  ky = sy - 32; }
    else if (sy < 80)  { W = Wvt; Wt = WtVT; K = 768;  ky = sy - 56; }
    else if (sy < 112) { W = Wkm; Wt = WtKM; K = 1024; ky = sy - 80; }
    else if (sy < 144) { W = Wvm; Wt = WtVM; K = 1024; ky = sy - 112; }
    else if (sy < 208) { W = Wkr; Wt = WtKR; K = 2048; ky = sy - 144; }
    else if (sy < 240) { W = Wvr; Wt = WtVR; K = 1024; ky = sy - 208; }
    else               { W = Wo;  Wt = WtO;  K = 1024; ky = sy - 240; }
    int n0 = blockIdx.x * 32, k0 = ky * 32;
    int tx = threadIdx.x & 31, ty = threadIdx.x >> 5;
    #pragma unroll
    for (int i = 0; i < 4; ++i)
        t[ty + i * 8][tx] = W[(long)(k0 + ty + i * 8) * 1024 + n0 + tx];
    __syncthreads();
    #pragma unroll
    for (int i = 0; i < 4; ++i)
        Wt[(long)(n0 + ty + i * 8) * K + k0 + tx] = f2s(t[tx][ty + i * 8]);
}

// ======================= MFMA GEMM (B^T layout, async LDS staging) ==========
// TR=false: C[token][feature].  TR=true: C^T store — C[feature*ldc + token].
constexpr int LDK = 64;

template <typename TC, bool TR = false>
__global__ __launch_bounds__(256) void gemm_bt(
    const short* __restrict__ A, int lda, long sA,
    const short* __restrict__ Bt, int ldb,
    const float* __restrict__ bias,
    const float* __restrict__ rowadd, int sRA,
    const float* __restrict__ rowmul, int sRM,
    const float* __restrict__ addC, int ldac, long sAC,
    TC* __restrict__ C, int ldc, long sC,
    int M, int K) {
    int bz = blockIdx.z;
    A += (long)bz * sA;
    C += (long)bz * sC;
    if (rowadd) rowadd += (long)bz * sRA;
    if (rowmul) rowmul += (long)bz * sRM;
    if (addC) addC += (long)bz * sAC;

    const int tm = blockIdx.y * 128;
    const int tn = blockIdx.x * 128;

    __shared__ __align__(16) short As[128 * LDK];
    __shared__ __align__(16) short Bs[128 * LDK];

    int tid = threadIdx.x;
    int lane = tid & 63, wid = tid >> 6;
    int wi = wid >> 1, wj = wid & 1;
    int l16 = lane & 15, quad = lane >> 4;

    f32x4 acc[4][4];
    #pragma unroll
    for (int i = 0; i < 4; ++i)
        #pragma unroll
        for (int j = 0; j < 4; ++j)
            acc[i][j] = (f32x4){0.f, 0.f, 0.f, 0.f};

    auto issue = [&](int k0) {
        #pragma unroll
        for (int p = 0; p < 4; ++p) {
            int e = p * 256 + tid;
            int row = e >> 3, c8 = e & 7;
            int gm = tm + row;
            if (gm >= M) gm = M - 1;  // clamp: garbage rows never stored
            gl_lds16(A + (long)gm * lda + k0 + c8 * 8, &As[row * LDK + c8 * 8]);
            gl_lds16(Bt + (long)(tn + row) * ldb + k0 + c8 * 8, &Bs[row * LDK + c8 * 8]);
        }
    };

    issue(0);
    int kt = 0;
    while (true) {
        __syncthreads();
        #pragma unroll
        for (int kk = 0; kk < 2; ++kk) {
            s16x8 af[4], bfr[4];
            #pragma unroll
            for (int i = 0; i < 4; ++i)
                af[i] = *(const s16x8*)&As[(wi * 64 + i * 16 + l16) * LDK + kk * 32 + quad * 8];
            #pragma unroll
            for (int j = 0; j < 4; ++j)
                bfr[j] = *(const s16x8*)&Bs[(wj * 64 + j * 16 + l16) * LDK + kk * 32 + quad * 8];
            #pragma unroll
            for (int i = 0; i < 4; ++i)
                #pragma unroll
                for (int j = 0; j < 4; ++j) {
                    if constexpr (TR)
                        acc[i][j] = __builtin_amdgcn_mfma_f32_16x16x32_bf16(bfr[j], af[i], acc[i][j], 0, 0, 0);
                    else
                        acc[i][j] = __builtin_amdgcn_mfma_f32_16x16x32_bf16(af[i], bfr[j], acc[i][j], 0, 0, 0);
                }
        }
        int nxt = kt + 64;
        if (nxt >= K) break;
        __syncthreads();
        issue(nxt);
        kt = nxt;
    }

    if constexpr (TR) {
        // acc[i][j]: D-row = feature (tile j, quad*4+r), D-col = token (tile i, l16)
        #pragma unroll
        for (int j = 0; j < 4; ++j) {
            #pragma unroll
            for (int r = 0; r < 4; ++r) {
                int feat = tn + wj * 64 + j * 16 + quad * 4 + r;
                float bf_ = bias ? bias[feat] : 0.f;
                #pragma unroll
                for (int i = 0; i < 4; ++i) {
                    int tok = tm + wi * 64 + i * 16 + l16;
                    if (tok >= M) continue;
                    float v = acc[i][j][r] + bf_ + (rowadd ? rowadd[tok] : 0.f);
                    v *= (rowmul ? rowmul[tok] : 1.f);
                    storef(&C[(long)feat * ldc + tok], v);
                }
            }
        }
    } else {
        #pragma unroll
        for (int i = 0; i < 4; ++i) {
            #pragma unroll
            for (int r = 0; r < 4; ++r) {
                int gm = tm + wi * 64 + i * 16 + quad * 4 + r;
                if (gm >= M) continue;
                float ra = rowadd ? rowadd[gm] : 0.f;
                float rm = rowmul ? rowmul[gm] : 1.f;
                #pragma unroll
                for (int j = 0; j < 4; ++j) {
                    int gn = tn + wj * 64 + j * 16 + l16;
                    float v = acc[i][j][r] + (bias ? bias[gn] : 0.f) + ra;
                    v *= rm;
                    if (addC) v += addC[(long)gm * ldac + gn];
                    storef(&C[(long)gm * ldc + gn], v);
                }
            }
        }
    }
}

// eo split-K
__global__ __launch_bounds__(256) void eo_partial(const float* __restrict__ emb,
                                                  const float* __restrict__ We,
                                                  float* __restrict__ part) {
    int nb = blockIdx.x;
    int ks = blockIdx.y;
    int n = nb * 256 + threadIdx.x;
    int k0 = ks * 64;
    __shared__ float a_s[8][64];
    for (int idx = threadIdx.x; idx < 512; idx += 256) {
        int b = idx >> 6, kk = idx & 63;
        float v = emb[b * 2048 + k0 + kk];
        a_s[b][kk] = v / (1.f + expf(-v));
    }
    __syncthreads();
    float acc[8] = {};
    for (int kk = 0; kk < 64; ++kk) {
        float w = We[(long)(k0 + kk) * 2048 + n];
        #pragma unroll
        for (int b = 0; b < 8; ++b) acc[b] = fmaf(a_s[b][kk], w, acc[b]);
    }
    #pragma unroll
    for (int b = 0; b < 8; ++b) part[((long)ks * 8 + b) * 2048 + n] = acc[b];
}

__global__ __launch_bounds__(256) void eo_reduce(const float* __restrict__ part,
                                                 const float* __restrict__ be,
                                                 float* __restrict__ eo) {
    int idx = blockIdx.x * 256 + threadIdx.x;
    int n = idx & 2047, b = idx >> 11;
    float s = be[n];
    #pragma unroll 8
    for (int ks = 0; ks < 32; ++ks) s += part[((long)ks * 8 + b) * 2048 + n];
    eo[idx] = s;
}

// q softmax over head dim (128): one wave per row, 2 elems/lane.
__global__ __launch_bounds__(256) void softmax_head(bf16* __restrict__ q) {
    long row = (long)blockIdx.x * 4 + (threadIdx.x >> 6);
    int lane = threadIdx.x & 63;
    bf16* p = q + row * 128 + lane * 2;
    float v0 = b2f(p[0]), v1 = b2f(p[1]);
    float mx = fmaxf(v0, v1);
    #pragma unroll
    for (int off = 32; off > 0; off >>= 1) mx = fmaxf(mx, __shfl_xor(mx, off, 64));
    float e0 = expf(v0 - mx), e1 = expf(v1 - mx);
    float s = e0 + e1;
    #pragma unroll
    for (int off = 32; off > 0; off >>= 1) s += __shfl_xor(s, off, 64);
    float inv = 1.f / s;
    p[0] = f2b(e0 * inv);
    p[1] = f2b(e1 * inv);
}

// key softmax column stats over tokens — ROW reduction on kT[b][d][n].
__global__ __launch_bounds__(256) void ksm_rows(const bf16* __restrict__ kT,
                                                float* __restrict__ cs_m,
                                                float* __restrict__ cs_inv) {
    int row = blockIdx.x * 4 + (threadIdx.x >> 6);  // b*1024 + feature
    int lane = threadIdx.x & 63;
    const s16x8* p8 = (const s16x8*)(kT + (long)row * NP);
    float m = -3.0e38f;
    for (int c = lane; c < NP / 8; c += 64) {
        s16x8 raw = p8[c];
        int n0 = c * 8;
        #pragma unroll
        for (int j = 0; j < 8; ++j)
            if (n0 + j < Nc) m = fmaxf(m, us2f((unsigned short)raw[j]));
    }
    #pragma unroll
    for (int off = 32; off > 0; off >>= 1) m = fmaxf(m, __shfl_xor(m, off, 64));
    float s = 0.f;
    for (int c = lane; c < NP / 8; c += 64) {
        s16x8 raw = p8[c];
        int n0 = c * 8;
        #pragma unroll
        for (int j = 0; j < 8; ++j)
            if (n0 + j < Nc) s += __expf(us2f((unsigned short)raw[j]) - m);
    }
    #pragma unroll
    for (int off = 32; off > 0; off >>= 1) s += __shfl_xor(s, off, 64);
    if (lane == 0) { cs_m[row] = m; cs_inv[row] = 1.f / s; }
}

// att_part[split][bh][l][d] = sum_{n in split} exp(kT[bd][n]-m_d) * vT[bl][n]  (C^T store)
constexpr int ATT_SPLIT = 4;
__global__ __launch_bounds__(256) void att_gemm(const bf16* __restrict__ kTb,
                                                const bf16* __restrict__ vTb,
                                                const float* __restrict__ cs_m,
                                                float* __restrict__ att_part) {
    int bh = blockIdx.x;
    int split = blockIdx.y;
    int b = bh >> 3, h = bh & 7;
    const short* A  = (const short*)kTb + ((long)b * 1024 + h * 128) * NP;
    const short* Bt = (const short*)vTb + ((long)b * 1024 + h * 128) * NP;
    float* ap = att_part + ((long)split * 64 + bh) * 16384;

    __shared__ __align__(16) short As[128 * LDK];
    __shared__ __align__(16) short Bs[128 * LDK];
    __shared__ float ms[128];

    int tid = threadIdx.x;
    if (tid < 128) ms[tid] = cs_m[(long)b * 1024 + h * 128 + tid];

    int lane = tid & 63, wid = tid >> 6;
    int wi = wid >> 1, wj = wid & 1;
    int l16 = lane & 15, quad = lane >> 4;

    f32x4 acc[4][4];
    #pragma unroll
    for (int i = 0; i < 4; ++i)
        #pragma unroll
        for (int j = 0; j < 4; ++j)
            acc[i][j] = (f32x4){0.f, 0.f, 0.f, 0.f};

    uint4 pa[4];
    auto computeA = [&](int k0) {
        #pragma unroll
        for (int p = 0; p < 4; ++p) {
            int e = p * 256 + tid;
            int row = e >> 3, c8 = e & 7;
            int n0 = k0 + c8 * 8;
            union { short s[8]; uint4 u; } pk;
            if (n0 >= Nc) {
                pk.u = (uint4){0u, 0u, 0u, 0u};
            } else {
                float m = ms[row];
                s16x8 raw = *(const s16x8*)(A + (long)row * NP + n0);
                #pragma unroll
                for (int j = 0; j < 8; ++j) {
                    float v = (n0 + j < Nc) ? __expf(us2f((unsigned short)raw[j]) - m) : 0.f;
                    pk.s[j] = f2s(v);
                }
            }
            pa[p] = pk.u;
        }
    };
    auto issueB = [&](int k0) {
        #pragma unroll
        for (int p = 0; p < 4; ++p) {
            int e = p * 256 + tid;
            int row = e >> 3, c8 = e & 7;
            int n0 = k0 + c8 * 8;
            if (n0 > NP - 8) n0 = NP - 8;  // clamp: A is zero there, values just must be finite
            gl_lds16(Bt + (long)row * NP + n0, &Bs[row * LDK + c8 * 8]);
        }
    };
    auto storeA = [&]() {
        #pragma unroll
        for (int p = 0; p < 4; ++p) {
            int e = p * 256 + tid;
            int row = e >> 3, c8 = e & 7;
            *(uint4*)&As[row * LDK + c8 * 8] = pa[p];
        }
    };

    // 34 K-steps total, split {9,9,8,8}
    int st = (split < 2) ? split * 9 : 18 + (split - 2) * 8;
    int cnt = (split < 2) ? 9 : 8;
    int kt = st * 64;
    int kend = kt + cnt * 64;

    __syncthreads();  // ms ready
    issueB(kt);
    computeA(kt);
    storeA();
    while (true) {
        __syncthreads();
        #pragma unroll
        for (int kk = 0; kk < 2; ++kk) {
            s16x8 af[4], bfr[4];
            #pragma unroll
            for (int i = 0; i < 4; ++i)
                af[i] = *(const s16x8*)&As[(wi * 64 + i * 16 + l16) * LDK + kk * 32 + quad * 8];
            #pragma unroll
            for (int j = 0; j < 4; ++j)
                bfr[j] = *(const s16x8*)&Bs[(wj * 64 + j * 16 + l16) * LDK + kk * 32 + quad * 8];
            #pragma unroll
            for (int i = 0; i < 4; ++i)
                #pragma unroll
                for (int j = 0; j < 4; ++j)
                    acc[i][j] = __builtin_amdgcn_mfma_f32_16x16x32_bf16(bfr[j], af[i], acc[i][j], 0, 0, 0);
        }
        int nxt = kt + 64;
        if (nxt >= kend) break;
        computeA(nxt);
        __syncthreads();
        issueB(nxt);
        storeA();
        kt = nxt;
    }

    // C^T: acc rows = value-feature l (tile j), cols = key-feature d (tile i)
    #pragma unroll
    for (int j = 0; j < 4; ++j) {
        #pragma unroll
        for (int r = 0; r < 4; ++r) {
            int l = wj * 64 + j * 16 + quad * 4 + r;
            #pragma unroll
            for (int i = 0; i < 4; ++i) {
                int d = wi * 64 + i * 16 + l16;
                ap[l * 128 + d] = acc[i][j][r];
            }
        }
    }
}

// reduce splits + apply per-d 1/sum -> bf16 attT[bh][l][d] (ready B^T operand for y)
__global__ __launch_bounds__(256) void reduce_att_t(const float* __restrict__ att_part,
                                                    const float* __restrict__ cs_inv,
                                                    bf16* __restrict__ attT) {
    long idx = (long)blockIdx.x * 256 + threadIdx.x;
    if (idx >= (long)64 * 16384) return;
    float s = 0.f;
    #pragma unroll
    for (int sp = 0; sp < ATT_SPLIT; ++sp) s += att_part[(long)sp * 64 * 16384 + idx];
    int bh = (int)(idx >> 14);
    int d = (int)(idx & 127);
    int b = bh >> 3, h = bh & 7;
    attT[idx] = f2b(s * cs_inv[b * Dc + h * 128 + d]);
}

// y[b,t,h*128+l] = sum_d q[b,t,h*128+d] * att[bh][d][l] — MFMA, K=128 single stage.
__global__ __launch_bounds__(256) void y_gemm(const bf16* __restrict__ q,
                                              const bf16* __restrict__ attT,
                                              bf16* __restrict__ y) {
    int bh = blockIdx.y;
    int b = bh >> 3, h = bh & 7;
    const short* A  = (const short*)q + (long)b * Tc * Dc + h * 128;   // row stride Dc
    const short* Bt = (const short*)attT + (long)bh * 16384;           // [l][d] stride 128
    bf16* yb = y + (long)b * Tc * Dc + h * 128;
    int tm = blockIdx.x * 128;

    __shared__ __align__(16) short As[128 * 128];
    __shared__ __align__(16) short Bs[128 * 128];
    int tid = threadIdx.x;
    #pragma unroll
    for (int p = 0; p < 8; ++p) {
        int e = p * 256 + tid;
        int row = e >> 4, c8 = e & 15;
        gl_lds16(A + (long)(tm + row) * Dc + c8 * 8, &As[row * 128 + c8 * 8]);
        gl_lds16(Bt + row * 128 + c8 * 8, &Bs[row * 128 + c8 * 8]);
    }
    int lane = tid & 63, wid = tid >> 6;
    int wi = wid >> 1, wj = wid & 1;
    int l16 = lane & 15, quad = lane >> 4;
    f32x4 acc[4][4];
    #pragma unroll
    for (int i = 0; i < 4; ++i)
        #pragma unroll
        for (int j = 0; j < 4; ++j)
            acc[i][j] = (f32x4){0.f, 0.f, 0.f, 0.f};
    __syncthreads();
    #pragma unroll
    for (int kk = 0; kk < 4; ++kk) {
        s16x8 af[4], bfr[4];
        #pragma unroll
        for (int i = 0; i < 4; ++i)
            af[i] = *(const s16x8*)&As[(wi * 64 + i * 16 + l16) * 128 + kk * 32 + quad * 8];
        #pragma unroll
        for (int j = 0; j < 4; ++j)
            bfr[j] = *(const s16x8*)&Bs[(wj * 64 + j * 16 + l16) * 128 + kk * 32 + quad * 8];
        #pragma unroll
        for (int i = 0; i < 4; ++i)
            #pragma unroll
            for (int j = 0; j < 4; ++j)
                acc[i][j] = __builtin_amdgcn_mfma_f32_16x16x32_bf16(af[i], bfr[j], acc[i][j], 0, 0, 0);
    }
    #pragma unroll
    for (int i = 0; i < 4; ++i) {
        #pragma unroll
        for (int r = 0; r < 4; ++r) {
            int gm = tm + wi * 64 + i * 16 + quad * 4 + r;
            #pragma unroll
            for (int j = 0; j < 4; ++j) {
                int gn = wj * 64 + j * 16 + l16;
                yb[(long)gm * Dc + gn] = f2b(acc[i][j][r]);
            }
        }
    }
}

// s = silu( LN(y)*(1+scale) + shift )
__global__ __launch_bounds__(256) void film_kernel(const bf16* __restrict__ y,
                                                   const float* __restrict__ eo,
                                                   const float* __restrict__ g,
                                                   const float* __restrict__ bta,
                                                   bf16* __restrict__ s) {
    long row = blockIdx.x;
    int b = (int)(row >> 10);
    const bf16* yr = y + row * Dc;
    float sum = 0.f, sum2 = 0.f;
    for (int c = threadIdx.x; c < Dc; c += 256) { float v = b2f(yr[c]); sum += v; sum2 += v * v; }
    float2 r = block_sum2(sum, sum2);
    float mean = r.x / Dc;
    float var = r.y / Dc - mean * mean;
    float inv = rsqrtf(var + 1e-5f);
    const float* sc = eo + (long)b * 2048;
    const float* sf = sc + 1024;
    bf16* so = s + row * Dc;
    for (int c = threadIdx.x; c < Dc; c += 256) {
        float v = (b2f(yr[c]) - mean) * inv * g[c] + bta[c];
        v = v * (1.f + sc[c]) + sf[c];
        so[c] = f2b(v / (1.f + expf(-v)));
    }
}

extern "C" void kernel_launch(void* const* d_in, const int* in_sizes, int n_in,
                              void* d_out, int out_size, void* d_ws, size_t ws_size,
                              hipStream_t stream) {
    if (ws_size < WS_NEED) return;

    const float* x         = (const float*)d_in[0];
    const float* xf        = (const float*)d_in[1];
    const float* emb       = (const float*)d_in[2];
    const float* src_mask  = (const float*)d_in[3];
    const int*   cond_type = (const int*)d_in[4];
    const float* re_motion = (const float*)d_in[5];
    const float* re_text   = (const float*)d_in[6];
    const float* re_mask   = (const float*)d_in[7];
    const float* ln_g  = (const float*)d_in[8];
    const float* ln_b  = (const float*)d_in[9];
    const float* tln_g = (const float*)d_in[10];
    const float* tln_b = (const float*)d_in[11];
    const float* rn1_g = (const float*)d_in[12];
    const float* rn1_b = (const float*)d_in[13];
    const float* rn2_g = (const float*)d_in[14];
    const float* rn2_b = (const float*)d_in[15];
    const float* Wq  = (const float*)d_in[16];
    const float* bq  = (const float*)d_in[17];
    const float* Wkt = (const float*)d_in[18];
    const float* bkt = (const float*)d_in[19];
    const float* Wvt = (const float*)d_in[20];
    const float* bvt = (const float*)d_in[21];
    const float* Wkm = (const float*)d_in[22];
    const float* bkm = (const float*)d_in[23];
    const float* Wvm = (const float*)d_in[24];
    const float* bvm = (const float*)d_in[25];
    const float* Wkr = (const float*)d_in[26];
    const float* bkr = (const float*)d_in[27];
    const float* Wvr = (const float*)d_in[28];
    const float* bvr = (const float*)d_in[29];
    const float* We  = (const float*)d_in[30];
    const float* be  = (const float*)d_in[31];
    const float* sln_g = (const float*)d_in[32];
    const float* sln_b = (const float*)d_in[33];
    const float* Wo  = (const float*)d_in[34];
    const float* bo  = (const float*)d_in[35];

    float* ws = (float*)d_ws;
    float* stats1   = ws + F_STATS1;
    float* stats2   = ws + F_STATS2;
    float* key_add  = ws + F_KEYADD;
    float* val_mul  = ws + F_VALMUL;
    float* cs_m     = ws + F_SILU;         // 8192
    float* cs_inv   = cs_m + Bc * Dc;      // 8192
    float* eo       = ws + F_EO;
    bf16*  attT     = (bf16*)(ws + F_ATT); // 2MB bf16 in 4MB slot
    bf16* wb = (bf16*)(ws + F_END);
    bf16* norm_x16 = wb + B_NORMX;
    bf16* q16      = wb + B_Q;
    bf16* kT16     = wb + B_KT;
    bf16* vT16     = wb + B_VT;
    bf16* nxf16    = wb + B_NXF;
    short* WtQ  = (short*)(wb + B_WQ);
    short* WtKT = (short*)(wb + B_WKT);
    short* WtVT = (short*)(wb + B_WVT);
    short* WtKM = (short*)(wb + B_WKM);
    short* WtVM = (short*)(wb + B_WVM);
    short* WtKR = (short*)(wb + B_WKR);
    short* WtVR = (short*)(wb + B_WVR);
    short* WtO  = (short*)(wb + B_WO);
    float* att_part = (float*)(wb + B_NORMX);  // overlays norm_x16 (dead by then)
    bf16* y16 = wb + B_NORMX;                  // written after att_part consumed
    bf16* s16 = q16;                           // q dead after y_gemm
    float* eo_part = (float*)(wb + B_VT);      // overlays vT16 (dead after att_gemm)
    bf16* ren1 = (bf16*)d_out;                 // 32MB scratch, dead before step 10
    bf16* ren2 = q16;                          // 16MB, consumed before Q gemm writes q16

    float* out = (float*)d_out;
    const long sKT = (long)Dc * NP;            // batch stride of kT/vT

    // 1. LayerNorms + stats
    ln_rows<bf16><<<dim3(Bc * Tc), dim3(256), 0, stream>>>(x, ln_g, ln_b, norm_x16, Dc);
    ln_rows<bf16><<<dim3(Bc * NTc), dim3(256), 0, stream>>>(xf, tln_g, tln_b, nxf16, LTc);
    ln_stats_both<<<dim3(Bc * KRc), dim3(256), 0, stream>>>(re_motion, re_text, stats1, stats2);

    // 2. Masks + vT pad zero-fill
    prep_masks<<<dim3((Bc * Nc + 255) / 256), dim3(256), 0, stream>>>(
        cond_type, src_mask, re_mask, key_add, val_mul);
    zero_tail<<<dim3((Bc * Dc + 255) / 256), dim3(256), 0, stream>>>(vT16);

    // 3. All weight transposes in one launch
    transpose_all<<<dim3(32, 272), dim3(256), 0, stream>>>(
        Wq, Wkt, Wvt, Wkm, Wvm, Wkr, Wvr, Wo,
        WtQ, WtKT, WtVT, WtKM, WtVM, WtKR, WtVR, WtO);

    // 4. Materialize normalized retrieval operands (once, bf16)
    materialize_ren<<<dim3(Bc * KRc), dim3(256), 0, stream>>>(
        re_motion, re_text, stats1, stats2, rn1_g, rn1_b, rn2_g, rn2_b, ren1, ren2);

    // 5. MFMA GEMMs — key/value to transposed [b][feature][token] layout
    gemm_bt<bf16, true><<<dim3(8, 1, Bc), dim3(256), 0, stream>>>(
        (const short*)nxf16, LTc, (long)NTc * LTc, WtKT, 768, bkt,
        key_add + 0, Nc, nullptr, 0, nullptr, 0, 0,
        kT16 + 0, NP, sKT, NTc, 768);
    gemm_bt<bf16, true><<<dim3(8, 8, Bc), dim3(256), 0, stream>>>(
        (const short*)ren1, 2048, (long)KRc * 2048, WtKR, 2048, bkr,
        key_add + NTc, Nc, nullptr, 0, nullptr, 0, 0,
        kT16 + NTc, NP, sKT, KRc, 2048);
    gemm_bt<bf16, true><<<dim3(8, 8, Bc), dim3(256), 0, stream>>>(
        (const short*)norm_x16, Dc, (long)Tc * Dc, WtKM, 1024, bkm,
        key_add + NTc + KRc, Nc, nullptr, 0, nullptr, 0, 0,
        kT16 + NTc + KRc, NP, sKT, Tc, 1024);
    gemm_bt<bf16, true><<<dim3(8, 1, Bc), dim3(256), 0, stream>>>(
        (const short*)nxf16, LTc, (long)NTc * LTc, WtVT, 768, bvt,
        nullptr, 0, val_mul + 0, Nc, nullptr, 0, 0,
        vT16 + 0, NP, sKT, NTc, 768);
    gemm_bt<bf16, true><<<dim3(8, 8, Bc), dim3(256), 0, stream>>>(
        (const short*)ren2, 1024, (long)KRc * 1024, WtVR, 1024, bvr,
        nullptr, 0, val_mul + NTc, Nc, nullptr, 0, 0,
        vT16 + NTc, NP, sKT, KRc, 1024);
    gemm_bt<bf16, true><<<dim3(8, 8, Bc), dim3(256), 0, stream>>>(
        (const short*)norm_x16, Dc, (long)Tc * Dc, WtVM, 1024, bvm,
        nullptr, 0, val_mul + NTc + KRc, Nc, nullptr, 0, 0,
        vT16 + NTc + KRc, NP, sKT, Tc, 1024);
    // Q last: it overwrites ren2's region (consumed by value_retr above)
    gemm_bt<bf16, false><<<dim3(8, 64, 1), dim3(256), 0, stream>>>(
        (const short*)norm_x16, Dc, 0, WtQ, 1024, bq, nullptr, 0, nullptr, 0,
        nullptr, 0, 0, q16, Dc, 0, Bc * Tc, 1024);

    // 6. Softmaxes
    softmax_head<<<dim3(Bc * Tc * Hc / 4), dim3(256), 0, stream>>>(q16);
    ksm_rows<<<dim3(Bc * Dc / 4), dim3(256), 0, stream>>>(kT16, cs_m, cs_inv);

    // 7. att = p^T v (MFMA, C^T store), reduce -> bf16 attT[bh][l][d]
    att_gemm<<<dim3(Bc * Hc, ATT_SPLIT), dim3(256), 0, stream>>>(kT16, vT16, cs_m, att_part);
    reduce_att_t<<<dim3((64 * 16384 + 255) / 256), dim3(256), 0, stream>>>(att_part, cs_inv, attT);

    // 8. y = q @ att (MFMA)
    y_gemm<<<dim3(Tc / 128, Bc * Hc), dim3(256), 0, stream>>>(q16, attT, y16);

    // 9. eo = silu(emb) @ We + be
    eo_partial<<<dim3(8, 32), dim3(256), 0, stream>>>(emb, We, eo_part);
    eo_reduce<<<dim3(64), dim3(256), 0, stream>>>(eo_part, be, eo);

    // 10. FiLM + silu
    film_kernel<<<dim3(Bc * Tc), dim3(256), 0, stream>>>(y16, eo, sln_g, sln_b, s16);

    // 11. out = x + s @ Wo + bo  (overwrites ren1 scratch fully)
    gemm_bt<float, false><<<dim3(8, 64, 1), dim3(256), 0, stream>>>(
        (const short*)s16, Dc, 0, WtO, 1024, bo, nullptr, 0, nullptr, 0,
        x, Dc, 0, out, Dc, 0, Bc * Tc, 1024);
}

// Round 3
// 695.267 us; speedup vs baseline: 1.2999x; 1.0203x over previous
//
#include <hip/hip_runtime.h>
#include <hip/hip_bf16.h>
#include <math.h>

using bf16 = __hip_bfloat16;

typedef short s16x8 __attribute__((ext_vector_type(8)));
typedef short s16x4 __attribute__((ext_vector_type(4)));
typedef float f32x4 __attribute__((ext_vector_type(4)));

// Problem dims (fixed by setup_inputs)
constexpr int Bc = 8, Tc = 1024, Dc = 1024, Hc = 8;
constexpr int NTc = 77, LTc = 768, KRc = 1024, Nc = 2125, Ec = 2048;
constexpr float NEGC = -1000000.0f;

// Transposed K/V layout: [b][feature(1024)][token], row stride NP (16B-aligned)
constexpr int NP = 2128;  // 2125 tokens + 3 pad (zeroed in vT; guarded in kT reads)
constexpr long SKT = (long)Dc * NP;

// ---- Workspace layout ----
constexpr long F_STATS1 = 0;                    // 16,384
constexpr long F_STATS2 = F_STATS1 + 16384;     // 16,384
constexpr long F_KEYADD = F_STATS2 + 16384;     // 17,000
constexpr long F_VALMUL = F_KEYADD + 17000;     // 17,000
constexpr long F_SILU   = F_VALMUL + 17000;     // 16,384 (cs_m[8192] + cs_inv[8192])
constexpr long F_EO     = F_SILU + 16384;       // 16,384
constexpr long F_ATT    = F_EO + 16384;         // 1,048,576 (holds attT bf16 2MB)
constexpr long F_END    = F_ATT + 1048576;
// bf16 region
constexpr long KT_SZ   = (long)Bc * Dc * NP;    // 17,432,576
constexpr long B_NORMX = 0;                     // 8,388,608 (reused: att_part fp32, then y16)
constexpr long B_Q     = B_NORMX + 8388608;     // 8,388,608 (ren2 first, then q16, then s16)
constexpr long B_KT    = B_Q + 8388608;         // kT  [b][d][n]
constexpr long B_VT    = B_KT + KT_SZ;          // vT  [b][l][n] (reused: eo_part fp32 after att)
constexpr long B_NXF   = B_VT + KT_SZ;          // 473,088
// Weights: Q, KM, VM contiguous (fused QKVM B-operand = 3072 rows x 1024)
constexpr long B_WQ    = B_NXF + 473088;
constexpr long B_WKM   = B_WQ + 1048576;
constexpr long B_WVM   = B_WKM + 1048576;
constexpr long B_WKT   = B_WVM + 1048576;
constexpr long B_WVT   = B_WKT + 786432;
constexpr long B_WKR   = B_WVT + 786432;
constexpr long B_WVR   = B_WKR + 2097152;
constexpr long B_WO    = B_WVR + 1048576;
constexpr long B_END   = B_WO + 1048576;
constexpr size_t WS_NEED = (size_t)F_END * 4 + (size_t)B_END * 2;

__device__ __forceinline__ float b2f(bf16 v) { return __bfloat162float(v); }
__device__ __forceinline__ bf16 f2b(float v) { return __float2bfloat16(v); }
__device__ __forceinline__ short f2s(float v) {
    bf16 h = __float2bfloat16(v);
    return *reinterpret_cast<short*>(&h);
}
__device__ __forceinline__ float us2f(unsigned short u) {
    bf16 h = *reinterpret_cast<bf16*>(&u);
    return __bfloat162float(h);
}
__device__ __forceinline__ void storef(float* p, float v) { *p = v; }
__device__ __forceinline__ void storef(bf16* p, float v) { *p = __float2bfloat16(v); }

// async global->LDS, 16B per lane. LDS dest must be wave-uniform base + lane*16.
typedef __attribute__((address_space(1))) const unsigned int gu32;
typedef __attribute__((address_space(3))) unsigned int lu32;
__device__ __forceinline__ void gl_lds16(const void* g, void* l) {
    __builtin_amdgcn_global_load_lds((gu32*)g, (lu32*)l, 16, 0, 0);
}

__device__ __forceinline__ float2 block_sum2(float s, float s2) {
    #pragma unroll
    for (int off = 32; off > 0; off >>= 1) {
        s  += __shfl_down(s, off, 64);
        s2 += __shfl_down(s2, off, 64);
    }
    __shared__ float sh[4], sh2[4];
    int w = threadIdx.x >> 6, lane = threadIdx.x & 63;
    if (lane == 0) { sh[w] = s; sh2[w] = s2; }
    __syncthreads();
    s = sh[0] + sh[1] + sh[2] + sh[3];
    s2 = sh2[0] + sh2[1] + sh2[2] + sh2[3];
    return make_float2(s, s2);
}

// Row LayerNorm: one block (256 thr) per row
template <typename TO>
__global__ __launch_bounds__(256) void ln_rows(const float* __restrict__ in,
                                               const float* __restrict__ g,
                                               const float* __restrict__ b,
                                               TO* __restrict__ out, int C) {
    long row = blockIdx.x;
    const float* x = in + row * (long)C;
    TO* o = out + row * (long)C;
    float s = 0.f, s2 = 0.f;
    for (int c = threadIdx.x; c < C; c += 256) { float v = x[c]; s += v; s2 += v * v; }
    float2 r = block_sum2(s, s2);
    float mean = r.x / C;
    float var = r.y / C - mean * mean;
    float inv = rsqrtf(var + 1e-5f);
    for (int c = threadIdx.x; c < C; c += 256)
        storef(&o[c], (x[c] - mean) * inv * g[c] + b[c]);
}

// Both retrieval LN stats in one pass over re_motion
__global__ __launch_bounds__(256) void ln_stats_both(const float* __restrict__ motion,
                                                     const float* __restrict__ text,
                                                     float* __restrict__ stats1,
                                                     float* __restrict__ stats2) {
    long row = blockIdx.x;  // b*1024 + k*512 + r
    const float* m = motion + row * 1024;
    const float* tx = text + (row >> 9) * 1024;
    float s = 0.f, s2 = 0.f;
    for (int c = threadIdx.x; c < 1024; c += 256) { float v = m[c]; s += v; s2 += v * v; }
    float2 rm = block_sum2(s, s2);
    __syncthreads();
    float st = 0.f, st2 = 0.f;
    for (int c = threadIdx.x; c < 1024; c += 256) { float v = tx[c]; st += v; st2 += v * v; }
    float2 rt = block_sum2(st, st2);
    if (threadIdx.x == 0) {
        float mean2 = rm.x / 1024.f;
        float var2 = rm.y / 1024.f - mean2 * mean2;
        stats2[2 * row] = mean2;
        stats2[2 * row + 1] = rsqrtf(var2 + 1e-5f);
        float mean1 = (rm.x + rt.x) / 2048.f;
        float var1 = (rm.y + rt.y) / 2048.f - mean1 * mean1;
        stats1[2 * row] = mean1;
        stats1[2 * row + 1] = rsqrtf(var1 + 1e-5f);
    }
}

// Materialize normalized retrieval operands as bf16 (once):
// ren1[row][0:1024] = LN1(motion), ren1[row][1024:2048] = LN1(text); ren2 = LN2(motion)
__device__ __forceinline__ s16x4 pack4(float4 v, float mean, float rstd, float4 g, float4 b) {
    s16x4 o;
    o[0] = f2s((v.x - mean) * rstd * g.x + b.x);
    o[1] = f2s((v.y - mean) * rstd * g.y + b.y);
    o[2] = f2s((v.z - mean) * rstd * g.z + b.z);
    o[3] = f2s((v.w - mean) * rstd * g.w + b.w);
    return o;
}
__global__ __launch_bounds__(256) void materialize_ren(
    const float* __restrict__ motion, const float* __restrict__ text,
    const float* __restrict__ stats1, const float* __restrict__ stats2,
    const float* __restrict__ g1, const float* __restrict__ b1,
    const float* __restrict__ g2, const float* __restrict__ b2,
    bf16* __restrict__ ren1, bf16* __restrict__ ren2) {
    long row = blockIdx.x;  // b*1024 + kr
    int c = threadIdx.x * 4;
    const float* mrow = motion + row * 1024;
    const float* trow = text + (row >> 9) * 1024;
    float m1 = stats1[2 * row], r1 = stats1[2 * row + 1];
    float m2 = stats2[2 * row], r2 = stats2[2 * row + 1];
    float4 mv = *(const float4*)(mrow + c);
    float4 tv = *(const float4*)(trow + c);
    float4 g1m = *(const float4*)(g1 + c),        b1m = *(const float4*)(b1 + c);
    float4 g1t = *(const float4*)(g1 + 1024 + c), b1t = *(const float4*)(b1 + 1024 + c);
    float4 g2m = *(const float4*)(g2 + c),        b2m = *(const float4*)(b2 + c);
    *(s16x4*)((short*)ren1 + row * 2048 + c)        = pack4(mv, m1, r1, g1m, b1m);
    *(s16x4*)((short*)ren1 + row * 2048 + 1024 + c) = pack4(tv, m1, r1, g1t, b1t);
    *(s16x4*)((short*)ren2 + row * 1024 + c)        = pack4(mv, m2, r2, g2m, b2m);
}

// Per-(b, n) key additive mask and value multiplicative mask
__global__ __launch_bounds__(256) void prep_masks(const int* __restrict__ cond_type,
                                                  const float* __restrict__ src_mask,
                                                  const float* __restrict__ re_mask,
                                                  float* __restrict__ key_add,
                                                  float* __restrict__ val_mul) {
    int idx = blockIdx.x * 256 + threadIdx.x;
    if (idx >= Bc * Nc) return;
    int b = idx / Nc, n = idx % Nc;
    int ct = cond_type[b];
    float text_ct = ((ct % 10) > 0) ? 1.f : 0.f;
    float retr_ct = ((ct / 10) > 0) ? 1.f : 0.f;
    float add, mul;
    if (n < NTc) {
        add = (1.f - text_ct) * NEGC; mul = text_ct;
    } else if (n < NTc + KRc) {
        float rm = re_mask[b * KRc + (n - NTc)];
        add = (1.f - retr_ct) * NEGC + (1.f - rm) * NEGC;
        mul = retr_ct * rm;
    } else {
        float sm = src_mask[b * Tc + (n - NTc - KRc)];
        add = (1.f - sm) * NEGC; mul = sm;
    }
    key_add[idx] = add;
    val_mul[idx] = mul;
}

// Zero the 3 pad columns of vT (keeps MFMA tail reads finite; kT pad is guarded)
__global__ __launch_bounds__(256) void zero_tail(bf16* __restrict__ vT) {
    int row = blockIdx.x * 256 + threadIdx.x;
    if (row >= Bc * Dc) return;
    bf16* p = vT + (long)row * NP + Nc;
    p[0] = f2b(0.f); p[1] = f2b(0.f); p[2] = f2b(0.f);
}

// All 8 weight transposes in ONE launch: W[K][1024] fp32 -> Wt[1024][K] bf16
// k-tile counts: Q:32 KT:24 VT:24 KM:32 VM:32 KR:64 VR:32 O:32 (cum 272)
__global__ __launch_bounds__(256) void transpose_all(
    const float* __restrict__ Wq,  const float* __restrict__ Wkt,
    const float* __restrict__ Wvt, const float* __restrict__ Wkm,
    const float* __restrict__ Wvm, const float* __restrict__ Wkr,
    const float* __restrict__ Wvr, const float* __restrict__ Wo,
    short* __restrict__ WtQ,  short* __restrict__ WtKT,
    short* __restrict__ WtVT, short* __restrict__ WtKM,
    short* __restrict__ WtVM, short* __restrict__ WtKR,
    short* __restrict__ WtVR, short* __restrict__ WtO) {
    __shared__ float t[32][33];
    int sy = blockIdx.y;
    const float* W; short* Wt; int K; int ky;
    if (sy < 32)       { W = Wq;  Wt = WtQ;  K = 1024; ky = sy; }
    else if (sy < 56)  { W = Wkt; Wt = WtKT; K = 768;  ky = sy - 32; }
    else if (sy < 80)  { W = Wvt; Wt = WtVT; K = 768;  ky = sy - 56; }
    else if (sy < 112) { W = Wkm; Wt = WtKM; K = 1024; ky = sy - 80; }
    else if (sy < 144) { W = Wvm; Wt = WtVM; K = 1024; ky = sy - 112; }
    else if (sy < 208) { W = Wkr; Wt = WtKR; K = 2048; ky = sy - 144; }
    else if (sy < 240) { W = Wvr; Wt = WtVR; K = 1024; ky = sy - 208; }
    else               { W = Wo;  Wt = WtO;  K = 1024; ky = sy - 240; }
    int n0 = blockIdx.x * 32, k0 = ky * 32;
    int tx = threadIdx.x & 31, ty = threadIdx.x >> 5;
    #pragma unroll
    for (int i = 0; i < 4; ++i)
        t[ty + i * 8][tx] = W[(long)(k0 + ty + i * 8) * 1024 + n0 + tx];
    __syncthreads();
    #pragma unroll
    for (int i = 0; i < 4; ++i)
        Wt[(long)(n0 + ty + i * 8) * K + k0 + tx] = f2s(t[tx][ty + i * 8]);
}

// ======================= MFMA GEMM (B^T layout, async LDS staging) ==========
constexpr int LDK = 64;

template <typename TC, bool TR = false>
__global__ __launch_bounds__(256) void gemm_bt(
    const short* __restrict__ A, int lda, long sA,
    const short* __restrict__ Bt, int ldb,
    const float* __restrict__ bias,
    const float* __restrict__ rowadd, int sRA,
    const float* __restrict__ rowmul, int sRM,
    const float* __restrict__ addC, int ldac, long sAC,
    TC* __restrict__ C, int ldc, long sC,
    int M, int K) {
    int bz = blockIdx.z;
    A += (long)bz * sA;
    C += (long)bz * sC;
    if (rowadd) rowadd += (long)bz * sRA;
    if (rowmul) rowmul += (long)bz * sRM;
    if (addC) addC += (long)bz * sAC;

    const int tm = blockIdx.y * 128;
    const int tn = blockIdx.x * 128;

    __shared__ __align__(16) short As[128 * LDK];
    __shared__ __align__(16) short Bs[128 * LDK];

    int tid = threadIdx.x;
    int lane = tid & 63, wid = tid >> 6;
    int wi = wid >> 1, wj = wid & 1;
    int l16 = lane & 15, quad = lane >> 4;

    f32x4 acc[4][4];
    #pragma unroll
    for (int i = 0; i < 4; ++i)
        #pragma unroll
        for (int j = 0; j < 4; ++j)
            acc[i][j] = (f32x4){0.f, 0.f, 0.f, 0.f};

    auto issue = [&](int k0) {
        #pragma unroll
        for (int p = 0; p < 4; ++p) {
            int e = p * 256 + tid;
            int row = e >> 3, c8 = e & 7;
            int gm = tm + row;
            if (gm >= M) gm = M - 1;  // clamp: garbage rows never stored
            gl_lds16(A + (long)gm * lda + k0 + c8 * 8, &As[row * LDK + c8 * 8]);
            gl_lds16(Bt + (long)(tn + row) * ldb + k0 + c8 * 8, &Bs[row * LDK + c8 * 8]);
        }
    };

    issue(0);
    int kt = 0;
    while (true) {
        __syncthreads();
        #pragma unroll
        for (int kk = 0; kk < 2; ++kk) {
            s16x8 af[4], bfr[4];
            #pragma unroll
            for (int i = 0; i < 4; ++i)
                af[i] = *(const s16x8*)&As[(wi * 64 + i * 16 + l16) * LDK + kk * 32 + quad * 8];
            #pragma unroll
            for (int j = 0; j < 4; ++j)
                bfr[j] = *(const s16x8*)&Bs[(wj * 64 + j * 16 + l16) * LDK + kk * 32 + quad * 8];
            #pragma unroll
            for (int i = 0; i < 4; ++i)
                #pragma unroll
                for (int j = 0; j < 4; ++j) {
                    if constexpr (TR)
                        acc[i][j] = __builtin_amdgcn_mfma_f32_16x16x32_bf16(bfr[j], af[i], acc[i][j], 0, 0, 0);
                    else
                        acc[i][j] = __builtin_amdgcn_mfma_f32_16x16x32_bf16(af[i], bfr[j], acc[i][j], 0, 0, 0);
                }
        }
        int nxt = kt + 64;
        if (nxt >= K) break;
        __syncthreads();
        issue(nxt);
        kt = nxt;
    }

    if constexpr (TR) {
        #pragma unroll
        for (int j = 0; j < 4; ++j) {
            #pragma unroll
            for (int r = 0; r < 4; ++r) {
                int feat = tn + wj * 64 + j * 16 + quad * 4 + r;
                float bf_ = bias ? bias[feat] : 0.f;
                #pragma unroll
                for (int i = 0; i < 4; ++i) {
                    int tok = tm + wi * 64 + i * 16 + l16;
                    if (tok >= M) continue;
                    float v = acc[i][j][r] + bf_ + (rowadd ? rowadd[tok] : 0.f);
                    v *= (rowmul ? rowmul[tok] : 1.f);
                    storef(&C[(long)feat * ldc + tok], v);
                }
            }
        }
    } else {
        #pragma unroll
        for (int i = 0; i < 4; ++i) {
            #pragma unroll
            for (int r = 0; r < 4; ++r) {
                int gm = tm + wi * 64 + i * 16 + quad * 4 + r;
                if (gm >= M) continue;
                float ra = rowadd ? rowadd[gm] : 0.f;
                float rm = rowmul ? rowmul[gm] : 1.f;
                #pragma unroll
                for (int j = 0; j < 4; ++j) {
                    int gn = tn + wj * 64 + j * 16 + l16;
                    float v = acc[i][j][r] + (bias ? bias[gn] : 0.f) + ra;
                    v *= rm;
                    if (addC) v += addC[(long)gm * ldac + gn];
                    storef(&C[(long)gm * ldc + gn], v);
                }
            }
        }
    }
}

// Fused Q + key_motion + value_motion: A = norm_x16 (8192x1024),
// B = [WtQ | WtKM | WtVM] (3072x1024). grid (24, 64) = 1536 blocks.
// sec = tn>>10: 0 -> q16 plain store; 1 -> kT TR store (+key_add); 2 -> vT TR store (*val_mul)
__global__ __launch_bounds__(256) void gemm_qkvm(
    const short* __restrict__ A, const short* __restrict__ Bt,
    const float* __restrict__ bq, const float* __restrict__ bkm,
    const float* __restrict__ bvm,
    const float* __restrict__ key_add, const float* __restrict__ val_mul,
    bf16* __restrict__ q16, bf16* __restrict__ kT, bf16* __restrict__ vT) {
    const int tm = blockIdx.y * 128;
    const int tn = blockIdx.x * 128;
    const int sec = tn >> 10;
    const int fn0 = tn & 1023;

    __shared__ __align__(16) short As[128 * LDK];
    __shared__ __align__(16) short Bs[128 * LDK];

    int tid = threadIdx.x;
    int lane = tid & 63, wid = tid >> 6;
    int wi = wid >> 1, wj = wid & 1;
    int l16 = lane & 15, quad = lane >> 4;

    f32x4 acc[4][4];
    #pragma unroll
    for (int i = 0; i < 4; ++i)
        #pragma unroll
        for (int j = 0; j < 4; ++j)
            acc[i][j] = (f32x4){0.f, 0.f, 0.f, 0.f};

    auto issue = [&](int k0) {
        #pragma unroll
        for (int p = 0; p < 4; ++p) {
            int e = p * 256 + tid;
            int row = e >> 3, c8 = e & 7;
            gl_lds16(A + (long)(tm + row) * 1024 + k0 + c8 * 8, &As[row * LDK + c8 * 8]);
            gl_lds16(Bt + (long)(tn + row) * 1024 + k0 + c8 * 8, &Bs[row * LDK + c8 * 8]);
        }
    };

    issue(0);
    int kt = 0;
    while (true) {
        __syncthreads();
        #pragma unroll
        for (int kk = 0; kk < 2; ++kk) {
            s16x8 af[4], bfr[4];
            #pragma unroll
            for (int i = 0; i < 4; ++i)
                af[i] = *(const s16x8*)&As[(wi * 64 + i * 16 + l16) * LDK + kk * 32 + quad * 8];
            #pragma unroll
            for (int j = 0; j < 4; ++j)
                bfr[j] = *(const s16x8*)&Bs[(wj * 64 + j * 16 + l16) * LDK + kk * 32 + quad * 8];
            if (sec == 0) {
                #pragma unroll
                for (int i = 0; i < 4; ++i)
                    #pragma unroll
                    for (int j = 0; j < 4; ++j)
                        acc[i][j] = __builtin_amdgcn_mfma_f32_16x16x32_bf16(af[i], bfr[j], acc[i][j], 0, 0, 0);
            } else {
                #pragma unroll
                for (int i = 0; i < 4; ++i)
                    #pragma unroll
                    for (int j = 0; j < 4; ++j)
                        acc[i][j] = __builtin_amdgcn_mfma_f32_16x16x32_bf16(bfr[j], af[i], acc[i][j], 0, 0, 0);
            }
        }
        int nxt = kt + 64;
        if (nxt >= 1024) break;
        __syncthreads();
        issue(nxt);
        kt = nxt;
    }

    if (sec == 0) {
        #pragma unroll
        for (int i = 0; i < 4; ++i) {
            #pragma unroll
            for (int r = 0; r < 4; ++r) {
                int gm = tm + wi * 64 + i * 16 + quad * 4 + r;
                #pragma unroll
                for (int j = 0; j < 4; ++j) {
                    int gn = fn0 + wj * 64 + j * 16 + l16;
                    q16[(long)gm * Dc + gn] = f2b(acc[i][j][r] + bq[gn]);
                }
            }
        }
    } else {
        const float* bias = (sec == 1) ? bkm : bvm;
        bf16* C = (sec == 1) ? kT : vT;
        #pragma unroll
        for (int j = 0; j < 4; ++j) {
            #pragma unroll
            for (int r = 0; r < 4; ++r) {
                int feat = fn0 + wj * 64 + j * 16 + quad * 4 + r;
                float bf_ = bias[feat];
                #pragma unroll
                for (int i = 0; i < 4; ++i) {
                    int gm = tm + wi * 64 + i * 16 + l16;
                    int b = gm >> 10, tok = gm & 1023;
                    int mi = b * Nc + NTc + KRc + tok;
                    float v = acc[i][j][r] + bf_;
                    if (sec == 1) v += key_add[mi];
                    else          v *= val_mul[mi];
                    C[(long)b * SKT + (long)feat * NP + NTc + KRc + tok] = f2b(v);
                }
            }
        }
    }
}

// Fused retrieval GEMMs: z<8 -> key_retr (K=2048), else value_retr (K=1024). grid (8,8,16)
__global__ __launch_bounds__(256) void gemm_retr(
    const short* __restrict__ ren1, const short* __restrict__ ren2,
    const short* __restrict__ WtKR, const short* __restrict__ WtVR,
    const float* __restrict__ bkr, const float* __restrict__ bvr,
    const float* __restrict__ key_add, const float* __restrict__ val_mul,
    bf16* __restrict__ kT, bf16* __restrict__ vT) {
    int z = blockIdx.z;
    bool isK = z < 8;
    int b = isK ? z : z - 8;
    const short* A  = isK ? ren1 + (long)b * KRc * 2048 : ren2 + (long)b * KRc * 1024;
    const short* Bt = isK ? WtKR : WtVR;
    int K = isK ? 2048 : 1024;
    const float* bias = isK ? bkr : bvr;
    const float* rmask = (isK ? key_add : val_mul) + b * Nc + NTc;
    bf16* C = (isK ? kT : vT) + (long)b * SKT + NTc;

    const int tm = blockIdx.y * 128;
    const int tn = blockIdx.x * 128;

    __shared__ __align__(16) short As[128 * LDK];
    __shared__ __align__(16) short Bs[128 * LDK];

    int tid = threadIdx.x;
    int lane = tid & 63, wid = tid >> 6;
    int wi = wid >> 1, wj = wid & 1;
    int l16 = lane & 15, quad = lane >> 4;

    f32x4 acc[4][4];
    #pragma unroll
    for (int i = 0; i < 4; ++i)
        #pragma unroll
        for (int j = 0; j < 4; ++j)
            acc[i][j] = (f32x4){0.f, 0.f, 0.f, 0.f};

    auto issue = [&](int k0) {
        #pragma unroll
        for (int p = 0; p < 4; ++p) {
            int e = p * 256 + tid;
            int row = e >> 3, c8 = e & 7;
            gl_lds16(A + (long)(tm + row) * K + k0 + c8 * 8, &As[row * LDK + c8 * 8]);
            gl_lds16(Bt + (long)(tn + row) * K + k0 + c8 * 8, &Bs[row * LDK + c8 * 8]);
        }
    };

    issue(0);
    int kt = 0;
    while (true) {
        __syncthreads();
        #pragma unroll
        for (int kk = 0; kk < 2; ++kk) {
            s16x8 af[4], bfr[4];
            #pragma unroll
            for (int i = 0; i < 4; ++i)
                af[i] = *(const s16x8*)&As[(wi * 64 + i * 16 + l16) * LDK + kk * 32 + quad * 8];
            #pragma unroll
            for (int j = 0; j < 4; ++j)
                bfr[j] = *(const s16x8*)&Bs[(wj * 64 + j * 16 + l16) * LDK + kk * 32 + quad * 8];
            #pragma unroll
            for (int i = 0; i < 4; ++i)
                #pragma unroll
                for (int j = 0; j < 4; ++j)
                    acc[i][j] = __builtin_amdgcn_mfma_f32_16x16x32_bf16(bfr[j], af[i], acc[i][j], 0, 0, 0);
        }
        int nxt = kt + 64;
        if (nxt >= K) break;
        __syncthreads();
        issue(nxt);
        kt = nxt;
    }

    #pragma unroll
    for (int j = 0; j < 4; ++j) {
        #pragma unroll
        for (int r = 0; r < 4; ++r) {
            int feat = tn + wj * 64 + j * 16 + quad * 4 + r;
            float bf_ = bias[feat];
            #pragma unroll
            for (int i = 0; i < 4; ++i) {
                int tok = tm + wi * 64 + i * 16 + l16;
                float v = acc[i][j][r] + bf_;
                if (isK) v += rmask[tok];
                else     v *= rmask[tok];
                C[(long)feat * NP + tok] = f2b(v);
            }
        }
    }
}

// eo split-K
__global__ __launch_bounds__(256) void eo_partial(const float* __restrict__ emb,
                                                  const float* __restrict__ We,
                                                  float* __restrict__ part) {
    int nb = blockIdx.x;
    int ks = blockIdx.y;
    int n = nb * 256 + threadIdx.x;
    int k0 = ks * 64;
    __shared__ float a_s[8][64];
    for (int idx = threadIdx.x; idx < 512; idx += 256) {
        int b = idx >> 6, kk = idx & 63;
        float v = emb[b * 2048 + k0 + kk];
        a_s[b][kk] = v / (1.f + expf(-v));
    }
    __syncthreads();
    float acc[8] = {};
    for (int kk = 0; kk < 64; ++kk) {
        float w = We[(long)(k0 + kk) * 2048 + n];
        #pragma unroll
        for (int b = 0; b < 8; ++b) acc[b] = fmaf(a_s[b][kk], w, acc[b]);
    }
    #pragma unroll
    for (int b = 0; b < 8; ++b) part[((long)ks * 8 + b) * 2048 + n] = acc[b];
}

__global__ __launch_bounds__(256) void eo_reduce(const float* __restrict__ part,
                                                 const float* __restrict__ be,
                                                 float* __restrict__ eo) {
    int idx = blockIdx.x * 256 + threadIdx.x;
    int n = idx & 2047, b = idx >> 11;
    float s = be[n];
    #pragma unroll 8
    for (int ks = 0; ks < 32; ++ks) s += part[((long)ks * 8 + b) * 2048 + n];
    eo[idx] = s;
}

// q softmax over head dim (128): one wave per row, 2 elems/lane.
__global__ __launch_bounds__(256) void softmax_head(bf16* __restrict__ q) {
    long row = (long)blockIdx.x * 4 + (threadIdx.x >> 6);
    int lane = threadIdx.x & 63;
    bf16* p = q + row * 128 + lane * 2;
    float v0 = b2f(p[0]), v1 = b2f(p[1]);
    float mx = fmaxf(v0, v1);
    #pragma unroll
    for (int off = 32; off > 0; off >>= 1) mx = fmaxf(mx, __shfl_xor(mx, off, 64));
    float e0 = expf(v0 - mx), e1 = expf(v1 - mx);
    float s = e0 + e1;
    #pragma unroll
    for (int off = 32; off > 0; off >>= 1) s += __shfl_xor(s, off, 64);
    float inv = 1.f / s;
    p[0] = f2b(e0 * inv);
    p[1] = f2b(e1 * inv);
}

// key softmax column stats over tokens — ROW reduction on kT[b][d][n].
__global__ __launch_bounds__(256) void ksm_rows(const bf16* __restrict__ kT,
                                                float* __restrict__ cs_m,
                                                float* __restrict__ cs_inv) {
    int row = blockIdx.x * 4 + (threadIdx.x >> 6);  // b*1024 + feature
    int lane = threadIdx.x & 63;
    const s16x8* p8 = (const s16x8*)(kT + (long)row * NP);
    float m = -3.0e38f;
    for (int c = lane; c < NP / 8; c += 64) {
        s16x8 raw = p8[c];
        int n0 = c * 8;
        #pragma unroll
        for (int j = 0; j < 8; ++j)
            if (n0 + j < Nc) m = fmaxf(m, us2f((unsigned short)raw[j]));
    }
    #pragma unroll
    for (int off = 32; off > 0; off >>= 1) m = fmaxf(m, __shfl_xor(m, off, 64));
    float s = 0.f;
    for (int c = lane; c < NP / 8; c += 64) {
        s16x8 raw = p8[c];
        int n0 = c * 8;
        #pragma unroll
        for (int j = 0; j < 8; ++j)
            if (n0 + j < Nc) s += __expf(us2f((unsigned short)raw[j]) - m);
    }
    #pragma unroll
    for (int off = 32; off > 0; off >>= 1) s += __shfl_xor(s, off, 64);
    if (lane == 0) { cs_m[row] = m; cs_inv[row] = 1.f / s; }
}

// att_part[split][bh][l][d] = sum_{n in split} exp(kT[bd][n]-m_d) * vT[bl][n]  (C^T store)
constexpr int ATT_SPLIT = 4;
__global__ __launch_bounds__(256) void att_gemm(const bf16* __restrict__ kTb,
                                                const bf16* __restrict__ vTb,
                                                const float* __restrict__ cs_m,
                                                float* __restrict__ att_part) {
    int bh = blockIdx.x;
    int split = blockIdx.y;
    int b = bh >> 3, h = bh & 7;
    const short* A  = (const short*)kTb + ((long)b * 1024 + h * 128) * NP;
    const short* Bt = (const short*)vTb + ((long)b * 1024 + h * 128) * NP;
    float* ap = att_part + ((long)split * 64 + bh) * 16384;

    __shared__ __align__(16) short As[128 * LDK];
    __shared__ __align__(16) short Bs[128 * LDK];
    __shared__ float ms[128];

    int tid = threadIdx.x;
    if (tid < 128) ms[tid] = cs_m[(long)b * 1024 + h * 128 + tid];

    int lane = tid & 63, wid = tid >> 6;
    int wi = wid >> 1, wj = wid & 1;
    int l16 = lane & 15, quad = lane >> 4;

    f32x4 acc[4][4];
    #pragma unroll
    for (int i = 0; i < 4; ++i)
        #pragma unroll
        for (int j = 0; j < 4; ++j)
            acc[i][j] = (f32x4){0.f, 0.f, 0.f, 0.f};

    uint4 pa[4];
    auto computeA = [&](int k0) {
        #pragma unroll
        for (int p = 0; p < 4; ++p) {
            int e = p * 256 + tid;
            int row = e >> 3, c8 = e & 7;
            int n0 = k0 + c8 * 8;
            union { short s[8]; uint4 u; } pk;
            if (n0 >= Nc) {
                pk.u = (uint4){0u, 0u, 0u, 0u};
            } else {
                float m = ms[row];
                s16x8 raw = *(const s16x8*)(A + (long)row * NP + n0);
                #pragma unroll
                for (int j = 0; j < 8; ++j) {
                    float v = (n0 + j < Nc) ? __expf(us2f((unsigned short)raw[j]) - m) : 0.f;
                    pk.s[j] = f2s(v);
                }
            }
            pa[p] = pk.u;
        }
    };
    auto issueB = [&](int k0) {
        #pragma unroll
        for (int p = 0; p < 4; ++p) {
            int e = p * 256 + tid;
            int row = e >> 3, c8 = e & 7;
            int n0 = k0 + c8 * 8;
            if (n0 > NP - 8) n0 = NP - 8;  // clamp: A is zero there, values just must be finite
            gl_lds16(Bt + (long)row * NP + n0, &Bs[row * LDK + c8 * 8]);
        }
    };
    auto storeA = [&]() {
        #pragma unroll
        for (int p = 0; p < 4; ++p) {
            int e = p * 256 + tid;
            int row = e >> 3, c8 = e & 7;
            *(uint4*)&As[row * LDK + c8 * 8] = pa[p];
        }
    };

    // 34 K-steps total, split {9,9,8,8}
    int st = (split < 2) ? split * 9 : 18 + (split - 2) * 8;
    int cnt = (split < 2) ? 9 : 8;
    int kt = st * 64;
    int kend = kt + cnt * 64;

    __syncthreads();  // ms ready
    issueB(kt);
    computeA(kt);
    storeA();
    while (true) {
        __syncthreads();
        #pragma unroll
        for (int kk = 0; kk < 2; ++kk) {
            s16x8 af[4], bfr[4];
            #pragma unroll
            for (int i = 0; i < 4; ++i)
                af[i] = *(const s16x8*)&As[(wi * 64 + i * 16 + l16) * LDK + kk * 32 + quad * 8];
            #pragma unroll
            for (int j = 0; j < 4; ++j)
                bfr[j] = *(const s16x8*)&Bs[(wj * 64 + j * 16 + l16) * LDK + kk * 32 + quad * 8];
            #pragma unroll
            for (int i = 0; i < 4; ++i)
                #pragma unroll
                for (int j = 0; j < 4; ++j)
                    acc[i][j] = __builtin_amdgcn_mfma_f32_16x16x32_bf16(bfr[j], af[i], acc[i][j], 0, 0, 0);
        }
        int nxt = kt + 64;
        if (nxt >= kend) break;
        computeA(nxt);
        __syncthreads();
        issueB(nxt);
        storeA();
        kt = nxt;
    }

    // C^T: acc rows = value-feature l (tile j), cols = key-feature d (tile i)
    #pragma unroll
    for (int j = 0; j < 4; ++j) {
        #pragma unroll
        for (int r = 0; r < 4; ++r) {
            int l = wj * 64 + j * 16 + quad * 4 + r;
            #pragma unroll
            for (int i = 0; i < 4; ++i) {
                int d = wi * 64 + i * 16 + l16;
                ap[l * 128 + d] = acc[i][j][r];
            }
        }
    }
}

// reduce splits + apply per-d 1/sum -> bf16 attT[bh][l][d] (ready B^T operand for y)
__global__ __launch_bounds__(256) void reduce_att_t(const float* __restrict__ att_part,
                                                    const float* __restrict__ cs_inv,
                                                    bf16* __restrict__ attT) {
    long idx = (long)blockIdx.x * 256 + threadIdx.x;
    if (idx >= (long)64 * 16384) return;
    float s = 0.f;
    #pragma unroll
    for (int sp = 0; sp < ATT_SPLIT; ++sp) s += att_part[(long)sp * 64 * 16384 + idx];
    int bh = (int)(idx >> 14);
    int d = (int)(idx & 127);
    int b = bh >> 3, h = bh & 7;
    attT[idx] = f2b(s * cs_inv[b * Dc + h * 128 + d]);
}

// y[b,t,h*128+l] = sum_d q[b,t,h*128+d] * att[bh][d][l] — MFMA, K=128 single stage.
__global__ __launch_bounds__(256) void y_gemm(const bf16* __restrict__ q,
                                              const bf16* __restrict__ attT,
                                              bf16* __restrict__ y) {
    int bh = blockIdx.y;
    int b = bh >> 3, h = bh & 7;
    const short* A  = (const short*)q + (long)b * Tc * Dc + h * 128;   // row stride Dc
    const short* Bt = (const short*)attT + (long)bh * 16384;           // [l][d] stride 128
    bf16* yb = y + (long)b * Tc * Dc + h * 128;
    int tm = blockIdx.x * 128;

    __shared__ __align__(16) short As[128 * 128];
    __shared__ __align__(16) short Bs[128 * 128];
    int tid = threadIdx.x;
    #pragma unroll
    for (int p = 0; p < 8; ++p) {
        int e = p * 256 + tid;
        int row = e >> 4, c8 = e & 15;
        gl_lds16(A + (long)(tm + row) * Dc + c8 * 8, &As[row * 128 + c8 * 8]);
        gl_lds16(Bt + row * 128 + c8 * 8, &Bs[row * 128 + c8 * 8]);
    }
    int lane = tid & 63, wid = tid >> 6;
    int wi = wid >> 1, wj = wid & 1;
    int l16 = lane & 15, quad = lane >> 4;
    f32x4 acc[4][4];
    #pragma unroll
    for (int i = 0; i < 4; ++i)
        #pragma unroll
        for (int j = 0; j < 4; ++j)
            acc[i][j] = (f32x4){0.f, 0.f, 0.f, 0.f};
    __syncthreads();
    #pragma unroll
    for (int kk = 0; kk < 4; ++kk) {
        s16x8 af[4], bfr[4];
        #pragma unroll
        for (int i = 0; i < 4; ++i)
            af[i] = *(const s16x8*)&As[(wi * 64 + i * 16 + l16) * 128 + kk * 32 + quad * 8];
        #pragma unroll
        for (int j = 0; j < 4; ++j)
            bfr[j] = *(const s16x8*)&Bs[(wj * 64 + j * 16 + l16) * 128 + kk * 32 + quad * 8];
        #pragma unroll
        for (int i = 0; i < 4; ++i)
            #pragma unroll
            for (int j = 0; j < 4; ++j)
                acc[i][j] = __builtin_amdgcn_mfma_f32_16x16x32_bf16(af[i], bfr[j], acc[i][j], 0, 0, 0);
    }
    #pragma unroll
    for (int i = 0; i < 4; ++i) {
        #pragma unroll
        for (int r = 0; r < 4; ++r) {
            int gm = tm + wi * 64 + i * 16 + quad * 4 + r;
            #pragma unroll
            for (int j = 0; j < 4; ++j) {
                int gn = wj * 64 + j * 16 + l16;
                yb[(long)gm * Dc + gn] = f2b(acc[i][j][r]);
            }
        }
    }
}

// s = silu( LN(y)*(1+scale) + shift )
__global__ __launch_bounds__(256) void film_kernel(const bf16* __restrict__ y,
                                                   const float* __restrict__ eo,
                                                   const float* __restrict__ g,
                                                   const float* __restrict__ bta,
                                                   bf16* __restrict__ s) {
    long row = blockIdx.x;
    int b = (int)(row >> 10);
    const bf16* yr = y + row * Dc;
    float sum = 0.f, sum2 = 0.f;
    for (int c = threadIdx.x; c < Dc; c += 256) { float v = b2f(yr[c]); sum += v; sum2 += v * v; }
    float2 r = block_sum2(sum, sum2);
    float mean = r.x / Dc;
    float var = r.y / Dc - mean * mean;
    float inv = rsqrtf(var + 1e-5f);
    const float* sc = eo + (long)b * 2048;
    const float* sf = sc + 1024;
    bf16* so = s + row * Dc;
    for (int c = threadIdx.x; c < Dc; c += 256) {
        float v = (b2f(yr[c]) - mean) * inv * g[c] + bta[c];
        v = v * (1.f + sc[c]) + sf[c];
        so[c] = f2b(v / (1.f + expf(-v)));
    }
}

extern "C" void kernel_launch(void* const* d_in, const int* in_sizes, int n_in,
                              void* d_out, int out_size, void* d_ws, size_t ws_size,
                              hipStream_t stream) {
    if (ws_size < WS_NEED) return;

    const float* x         = (const float*)d_in[0];
    const float* xf        = (const float*)d_in[1];
    const float* emb       = (const float*)d_in[2];
    const float* src_mask  = (const float*)d_in[3];
    const int*   cond_type = (const int*)d_in[4];
    const float* re_motion = (const float*)d_in[5];
    const float* re_text   = (const float*)d_in[6];
    const float* re_mask   = (const float*)d_in[7];
    const float* ln_g  = (const float*)d_in[8];
    const float* ln_b  = (const float*)d_in[9];
    const float* tln_g = (const float*)d_in[10];
    const float* tln_b = (const float*)d_in[11];
    const float* rn1_g = (const float*)d_in[12];
    const float* rn1_b = (const float*)d_in[13];
    const float* rn2_g = (const float*)d_in[14];
    const float* rn2_b = (const float*)d_in[15];
    const float* Wq  = (const float*)d_in[16];
    const float* bq  = (const float*)d_in[17];
    const float* Wkt = (const float*)d_in[18];
    const float* bkt = (const float*)d_in[19];
    const float* Wvt = (const float*)d_in[20];
    const float* bvt = (const float*)d_in[21];
    const float* Wkm = (const float*)d_in[22];
    const float* bkm = (const float*)d_in[23];
    const float* Wvm = (const float*)d_in[24];
    const float* bvm = (const float*)d_in[25];
    const float* Wkr = (const float*)d_in[26];
    const float* bkr = (const float*)d_in[27];
    const float* Wvr = (const float*)d_in[28];
    const float* bvr = (const float*)d_in[29];
    const float* We  = (const float*)d_in[30];
    const float* be  = (const float*)d_in[31];
    const float* sln_g = (const float*)d_in[32];
    const float* sln_b = (const float*)d_in[33];
    const float* Wo  = (const float*)d_in[34];
    const float* bo  = (const float*)d_in[35];

    float* ws = (float*)d_ws;
    float* stats1   = ws + F_STATS1;
    float* stats2   = ws + F_STATS2;
    float* key_add  = ws + F_KEYADD;
    float* val_mul  = ws + F_VALMUL;
    float* cs_m     = ws + F_SILU;         // 8192
    float* cs_inv   = cs_m + Bc * Dc;      // 8192
    float* eo       = ws + F_EO;
    bf16*  attT     = (bf16*)(ws + F_ATT); // 2MB bf16 in 4MB slot
    bf16* wb = (bf16*)(ws + F_END);
    bf16* norm_x16 = wb + B_NORMX;
    bf16* q16      = wb + B_Q;
    bf16* kT16     = wb + B_KT;
    bf16* vT16     = wb + B_VT;
    bf16* nxf16    = wb + B_NXF;
    short* WtQ  = (short*)(wb + B_WQ);     // WtQ/WtKM/WtVM contiguous = QKVM B-operand
    short* WtKM = (short*)(wb + B_WKM);
    short* WtVM = (short*)(wb + B_WVM);
    short* WtKT = (short*)(wb + B_WKT);
    short* WtVT = (short*)(wb + B_WVT);
    short* WtKR = (short*)(wb + B_WKR);
    short* WtVR = (short*)(wb + B_WVR);
    short* WtO  = (short*)(wb + B_WO);
    float* att_part = (float*)(wb + B_NORMX);  // overlays norm_x16 (dead by then)
    bf16* y16 = wb + B_NORMX;                  // written after att_part consumed
    bf16* s16 = q16;                           // q dead after y_gemm
    float* eo_part = (float*)(wb + B_VT);      // overlays vT16 (dead after att_gemm)
    bf16* ren1 = (bf16*)d_out;                 // 32MB scratch, dead before final out
    bf16* ren2 = q16;                          // consumed by gemm_retr before qkvm writes q16

    float* out = (float*)d_out;
    const long sKT = SKT;

    // 1. LayerNorms + stats
    ln_rows<bf16><<<dim3(Bc * Tc), dim3(256), 0, stream>>>(x, ln_g, ln_b, norm_x16, Dc);
    ln_rows<bf16><<<dim3(Bc * NTc), dim3(256), 0, stream>>>(xf, tln_g, tln_b, nxf16, LTc);
    ln_stats_both<<<dim3(Bc * KRc), dim3(256), 0, stream>>>(re_motion, re_text, stats1, stats2);

    // 2. Masks + vT pad zero-fill
    prep_masks<<<dim3((Bc * Nc + 255) / 256), dim3(256), 0, stream>>>(
        cond_type, src_mask, re_mask, key_add, val_mul);
    zero_tail<<<dim3((Bc * Dc + 255) / 256), dim3(256), 0, stream>>>(vT16);

    // 3. All weight transposes in one launch
    transpose_all<<<dim3(32, 272), dim3(256), 0, stream>>>(
        Wq, Wkt, Wvt, Wkm, Wvm, Wkr, Wvr, Wo,
        WtQ, WtKT, WtVT, WtKM, WtVM, WtKR, WtVR, WtO);

    // 4. Materialize normalized retrieval operands (once, bf16)
    materialize_ren<<<dim3(Bc * KRc), dim3(256), 0, stream>>>(
        re_motion, re_text, stats1, stats2, rn1_g, rn1_b, rn2_g, rn2_b, ren1, ren2);

    // 5. Text key/value GEMMs (small)
    gemm_bt<bf16, true><<<dim3(8, 1, Bc), dim3(256), 0, stream>>>(
        (const short*)nxf16, LTc, (long)NTc * LTc, WtKT, 768, bkt,
        key_add + 0, Nc, nullptr, 0, nullptr, 0, 0,
        kT16 + 0, NP, sKT, NTc, 768);
    gemm_bt<bf16, true><<<dim3(8, 1, Bc), dim3(256), 0, stream>>>(
        (const short*)nxf16, LTc, (long)NTc * LTc, WtVT, 768, bvt,
        nullptr, 0, val_mul + 0, Nc, nullptr, 0, 0,
        vT16 + 0, NP, sKT, NTc, 768);

    // 6. Fused retrieval GEMMs (KR + VR, 1024 blocks). Must precede qkvm (ren2 = q16 region).
    gemm_retr<<<dim3(8, 8, 16), dim3(256), 0, stream>>>(
        (const short*)ren1, (const short*)ren2, WtKR, WtVR, bkr, bvr,
        key_add, val_mul, kT16, vT16);

    // 7. Fused Q + KM + VM (1536 blocks)
    gemm_qkvm<<<dim3(24, 64), dim3(256), 0, stream>>>(
        (const short*)norm_x16, WtQ, bq, bkm, bvm, key_add, val_mul,
        q16, kT16, vT16);

    // 8. Softmaxes
    softmax_head<<<dim3(Bc * Tc * Hc / 4), dim3(256), 0, stream>>>(q16);
    ksm_rows<<<dim3(Bc * Dc / 4), dim3(256), 0, stream>>>(kT16, cs_m, cs_inv);

    // 9. att = p^T v (MFMA, C^T store), reduce -> bf16 attT[bh][l][d]
    att_gemm<<<dim3(Bc * Hc, ATT_SPLIT), dim3(256), 0, stream>>>(kT16, vT16, cs_m, att_part);
    reduce_att_t<<<dim3((64 * 16384 + 255) / 256), dim3(256), 0, stream>>>(att_part, cs_inv, attT);

    // 10. y = q @ att (MFMA)
    y_gemm<<<dim3(Tc / 128, Bc * Hc), dim3(256), 0, stream>>>(q16, attT, y16);

    // 11. eo = silu(emb) @ We + be
    eo_partial<<<dim3(8, 32), dim3(256), 0, stream>>>(emb, We, eo_part);
    eo_reduce<<<dim3(64), dim3(256), 0, stream>>>(eo_part, be, eo);

    // 12. FiLM + silu
    film_kernel<<<dim3(Bc * Tc), dim3(256), 0, stream>>>(y16, eo, sln_g, sln_b, s16);

    // 13. out = x + s @ Wo + bo  (overwrites ren1 scratch fully)
    gemm_bt<float, false><<<dim3(8, 64, 1), dim3(256), 0, stream>>>(
        (const short*)s16, Dc, 0, WtO, 1024, bo, nullptr, 0, nullptr, 0,
        x, Dc, 0, out, Dc, 0, Bc * Tc, 1024);
}